// Round 1
// baseline (274.952 us; speedup 1.0000x reference)
//
#include <hip/hip_runtime.h>

// ---------------------------------------------------------------------------
// Fused attention block: qkv-proj -> RoPE -> softmax attention -> out-proj
// B=8 N=1024 C=1024 H=16 D=64.  All matmuls in bf16 MFMA (16x16x32), fp32 acc.
// Threshold is 2% of max|ref| -> bf16 pipeline is numerically safe.
// ---------------------------------------------------------------------------

typedef __attribute__((ext_vector_type(8))) short bf16x8;   // 8 bf16 = 4 VGPRs
typedef __attribute__((ext_vector_type(4))) float floatx4;

__device__ __forceinline__ void gld16(const void* g, void* l) {
  // async global->LDS, 16B per lane; LDS dest must be wave-uniform base.
  __builtin_amdgcn_global_load_lds((const __attribute__((address_space(1))) void*)g,
                                   (__attribute__((address_space(3))) void*)l, 16, 0, 0);
}

__device__ __forceinline__ short f2bf(float f) {          // RNE fp32->bf16
  unsigned u = __builtin_bit_cast(unsigned, f);
  u = (u + 0x7FFFu + ((u >> 16) & 1u)) >> 16;
  return (short)u;
}
__device__ __forceinline__ float bf2f(short s) {
  unsigned u = ((unsigned)(unsigned short)s) << 16;
  return __builtin_bit_cast(float, u);
}

// ---------------- fp32 -> bf16 convert (vectorized) ----------------
__global__ __launch_bounds__(256) void cvt_bf16(const float* __restrict__ src,
                                                short* __restrict__ dst, int n4) {
  int i = blockIdx.x * 256 + threadIdx.x;
  if (i < n4) {
    float4 v = reinterpret_cast<const float4*>(src)[i];
    short4 o;
    o.x = f2bf(v.x); o.y = f2bf(v.y); o.z = f2bf(v.z); o.w = f2bf(v.w);
    reinterpret_cast<short4*>(dst)[i] = o;
  }
}

// ---------------- RoPE cos/sin table: [N=1024][D=64] -> float2 ----------------
__global__ __launch_bounds__(256) void rope_table(const float* __restrict__ f,
                                                  float2* __restrict__ tbl) {
  int i = blockIdx.x * 256 + threadIdx.x;   // 65536
  float v = f[i];
  tbl[i] = make_float2(cosf(v), sinf(v));
}

// scale (D^-0.5 = 1/8) * log2(e), folded into q so softmax uses exp2 (v_exp_f32)
#define QSCALE 0.18033688011112042f

// in-place RoPE on q (with QSCALE) and k, bf16. idx over B*H*N*32 pairs.
__global__ __launch_bounds__(256) void rope_apply(short* __restrict__ q,
                                                  short* __restrict__ k,
                                                  const float2* __restrict__ tbl) {
  int idx = blockIdx.x * 256 + threadIdx.x;
  int row = idx >> 5;           // bh*1024 + n
  int dp  = idx & 31;
  int n   = row & 1023;
  float2 c1 = tbl[n * 64 + dp];
  float2 c2 = tbl[n * 64 + dp + 32];
  size_t base = (size_t)row * 64;
  float q1 = bf2f(q[base + dp]), q2 = bf2f(q[base + dp + 32]);
  q[base + dp]      = f2bf((q1 * c1.x - q2 * c1.y) * QSCALE);
  q[base + dp + 32] = f2bf((q2 * c2.x + q1 * c2.y) * QSCALE);
  float k1 = bf2f(k[base + dp]), k2 = bf2f(k[base + dp + 32]);
  k[base + dp]      = f2bf(k1 * c1.x - k2 * c1.y);
  k[base + dp + 32] = f2bf(k2 * c2.x + k1 * c2.y);
}

// ---------------- GEMM core: C[128x128] = A[128xK] * B[128xK]^T, K=1024 ----------------
// BK=64, 4 waves (2x2), per-wave 64x64 = 4x4 frags of 16x16x32 bf16 MFMA.
// LDS rows XOR-swizzled in 16B chunks (chunk ^= row&7) via pre-swizzled global src.
__device__ __forceinline__ void gemm_main(const short* __restrict__ A,
                                          const short* __restrict__ Bm,
                                          short* As, short* Bs,
                                          floatx4 (&acc)[4][4]) {
  const int tid = threadIdx.x;
  const int wid = tid >> 6, lane = tid & 63;
  const int g = lane >> 4, l15 = lane & 15;
  const int wr = wid >> 1, wc = wid & 1;
  const size_t trow = (size_t)blockIdx.y * 128, tcol = (size_t)blockIdx.x * 128;
  floatx4 zero = {0.f, 0.f, 0.f, 0.f};
  #pragma unroll
  for (int i = 0; i < 4; ++i)
    #pragma unroll
    for (int j = 0; j < 4; ++j) acc[i][j] = zero;

  for (int k0 = 0; k0 < 1024; k0 += 64) {
    #pragma unroll
    for (int i = 0; i < 4; ++i) {
      const int cb = (i * 4 + wid) * 64;        // wave-uniform chunk base
      const int c  = cb + lane;                 // 16B chunk index 0..1023
      const int r  = c >> 3, s = c & 7;         // row, chunk-in-row (8x16B = 128B row)
      const int koff = k0 + ((s ^ (r & 7)) << 3);  // pre-swizzled global source
      gld16(A  + (trow + r) * 1024 + koff, As + (size_t)cb * 8);
      gld16(Bm + (tcol + r) * 1024 + koff, Bs + (size_t)cb * 8);
    }
    __syncthreads();
    #pragma unroll
    for (int ks = 0; ks < 2; ++ks) {
      bf16x8 af[4], bfr[4];
      #pragma unroll
      for (int mi = 0; mi < 4; ++mi) {
        int row = wr * 64 + mi * 16 + l15;
        int ch  = (ks * 4 + g) ^ (row & 7);
        af[mi] = *reinterpret_cast<const bf16x8*>(As + row * 64 + ch * 8);
      }
      #pragma unroll
      for (int nt = 0; nt < 4; ++nt) {
        int row = wc * 64 + nt * 16 + l15;
        int ch  = (ks * 4 + g) ^ (row & 7);
        bfr[nt] = *reinterpret_cast<const bf16x8*>(Bs + row * 64 + ch * 8);
      }
      #pragma unroll
      for (int mi = 0; mi < 4; ++mi)
        #pragma unroll
        for (int nt = 0; nt < 4; ++nt)
          acc[mi][nt] = __builtin_amdgcn_mfma_f32_16x16x32_bf16(af[mi], bfr[nt],
                                                                acc[mi][nt], 0, 0, 0);
    }
    __syncthreads();
  }
}

// QKV GEMM: A = x_bf16 [8192x1024], B = qkv_w_bf16 [3072x1024].
// Epilogue scatters to q/k/v [(b*16+h)][n][d] bf16 (no RoPE yet).
__global__ __launch_bounds__(256) void gemm_qkv_k(const short* __restrict__ A,
                                                  const short* __restrict__ Bm,
                                                  short* __restrict__ qo,
                                                  short* __restrict__ ko,
                                                  short* __restrict__ vo) {
  __shared__ __align__(16) short As[128 * 64];
  __shared__ __align__(16) short Bs[128 * 64];
  floatx4 acc[4][4];
  gemm_main(A, Bm, As, Bs, acc);

  const int tid = threadIdx.x;
  const int wid = tid >> 6, lane = tid & 63;
  const int g = lane >> 4, l15 = lane & 15;
  const int wr = wid >> 1, wc = wid & 1;
  const int trow = blockIdx.y * 128, tcol = blockIdx.x * 128;
  #pragma unroll
  for (int nt = 0; nt < 4; ++nt) {
    int col = tcol + wc * 64 + nt * 16 + l15;   // D-layout: col = lane&15
    int which = col >> 10, hc = col & 1023;
    short* dst = which == 0 ? qo : (which == 1 ? ko : vo);
    int h = hc >> 6, d = hc & 63;
    #pragma unroll
    for (int mi = 0; mi < 4; ++mi)
      #pragma unroll
      for (int r = 0; r < 4; ++r) {
        int rowg = trow + wr * 64 + mi * 16 + g * 4 + r;   // row = (lane>>4)*4+reg
        int b = rowg >> 10, n = rowg & 1023;
        dst[((size_t)(b * 16 + h) * 1024 + n) * 64 + d] = f2bf(acc[mi][nt][r]);
      }
  }
}

// Proj GEMM: A = attn_out bf16 [8192x1024], B = proj_w bf16 [1024x1024], +bias, fp32 out.
__global__ __launch_bounds__(256) void gemm_proj_k(const short* __restrict__ A,
                                                   const short* __restrict__ Bm,
                                                   const float* __restrict__ pb,
                                                   float* __restrict__ out) {
  __shared__ __align__(16) short As[128 * 64];
  __shared__ __align__(16) short Bs[128 * 64];
  floatx4 acc[4][4];
  gemm_main(A, Bm, As, Bs, acc);

  const int tid = threadIdx.x;
  const int wid = tid >> 6, lane = tid & 63;
  const int g = lane >> 4, l15 = lane & 15;
  const int wr = wid >> 1, wc = wid & 1;
  const int trow = blockIdx.y * 128, tcol = blockIdx.x * 128;
  #pragma unroll
  for (int nt = 0; nt < 4; ++nt) {
    int col = tcol + wc * 64 + nt * 16 + l15;
    float bias = pb[col];
    #pragma unroll
    for (int mi = 0; mi < 4; ++mi)
      #pragma unroll
      for (int r = 0; r < 4; ++r) {
        int rowg = trow + wr * 64 + mi * 16 + g * 4 + r;
        out[(size_t)rowg * 1024 + col] = acc[mi][nt][r] + bias;
      }
  }
}

// ---------------- flash attention ----------------
// grid: (16 q-tiles of 64 rows, 128 bh). 4 waves x 16 q-rows each. KV tile = 64.
// q pre-scaled by 0.125*log2e -> softmax via exp2f.
__global__ __launch_bounds__(256) void attn_kernel(const short* __restrict__ qs,
                                                   const short* __restrict__ ksrc,
                                                   const short* __restrict__ vs,
                                                   short* __restrict__ aout) {
  __shared__ __align__(16) short Klds[64 * 64];     // [k][d], rows chunk-swizzled
  __shared__ __align__(16) short Vt[64 * 72];       // V^T [d][k], pad 72 (144B rows)
  __shared__ __align__(16) short Plds[4][16 * 72];  // per-wave P [q][k], pad 72

  const int tid = threadIdx.x, wid = tid >> 6, lane = tid & 63;
  const int g = lane >> 4, l15 = lane & 15;
  const int bh = blockIdx.y, q0 = blockIdx.x * 64;
  const size_t bhoff = (size_t)bh * 1024 * 64;

  // Q fragments (A-operand): row q = lane&15, kc = ds*32 + g*8 + j
  const short* Qp = qs + bhoff + (size_t)(q0 + wid * 16 + l15) * 64 + g * 8;
  bf16x8 qf0 = *reinterpret_cast<const bf16x8*>(Qp);
  bf16x8 qf1 = *reinterpret_cast<const bf16x8*>(Qp + 32);

  floatx4 o[4];
  float mrun[4], lrun[4];
  floatx4 zero = {0.f, 0.f, 0.f, 0.f};
  #pragma unroll
  for (int i = 0; i < 4; ++i) { o[i] = zero; mrun[i] = -1e30f; lrun[i] = 0.f; }

  const short* Kb = ksrc + bhoff;
  const short* Vb = vs + bhoff;
  const int vrow = tid >> 2, vc0 = (tid & 3) * 16;

  for (int t = 0; t < 16; ++t) {
    // ---- stage K tile [64][64] via swizzled global_load_lds ----
    #pragma unroll
    for (int i = 0; i < 2; ++i) {
      const int cb = (i * 4 + wid) * 64;
      const int c  = cb + lane;
      const int r  = c >> 3, s = c & 7;
      gld16(Kb + (size_t)(t * 64 + r) * 64 + ((s ^ (r & 7)) << 3),
            Klds + (size_t)cb * 8);
    }
    // ---- stage V^T [d][k] (reg transpose) ----
    const short* vp = Vb + (size_t)(t * 64 + vrow) * 64 + vc0;
    bf16x8 v0 = *reinterpret_cast<const bf16x8*>(vp);
    bf16x8 v1 = *reinterpret_cast<const bf16x8*>(vp + 8);
    #pragma unroll
    for (int j = 0; j < 8; ++j) {
      Vt[(vc0 + j) * 72 + vrow]     = v0[j];
      Vt[(vc0 + 8 + j) * 72 + vrow] = v1[j];
    }
    __syncthreads();

    // ---- S = Q K^T (scaled-log2 domain): D[m=q][n=k], 8 MFMA ----
    floatx4 s4[4];
    #pragma unroll
    for (int kt = 0; kt < 4; ++kt) s4[kt] = zero;
    #pragma unroll
    for (int kt = 0; kt < 4; ++kt) {
      int krow = kt * 16 + l15;
      int ch0 = g ^ (krow & 7);
      bf16x8 kf0 = *reinterpret_cast<const bf16x8*>(Klds + krow * 64 + ch0 * 8);
      s4[kt] = __builtin_amdgcn_mfma_f32_16x16x32_bf16(qf0, kf0, s4[kt], 0, 0, 0);
      int ch1 = (4 + g) ^ (krow & 7);
      bf16x8 kf1 = *reinterpret_cast<const bf16x8*>(Klds + krow * 64 + ch1 * 8);
      s4[kt] = __builtin_amdgcn_mfma_f32_16x16x32_bf16(qf1, kf1, s4[kt], 0, 0, 0);
    }

    // ---- online softmax: rows q = g*4+r, reduce over 16 lanes (bits 0-3) ----
    float mnew[4], alpha[4], lsum[4];
    #pragma unroll
    for (int r = 0; r < 4; ++r) {
      float m0 = fmaxf(fmaxf(s4[0][r], s4[1][r]), fmaxf(s4[2][r], s4[3][r]));
      m0 = fmaxf(m0, __shfl_xor(m0, 1));
      m0 = fmaxf(m0, __shfl_xor(m0, 2));
      m0 = fmaxf(m0, __shfl_xor(m0, 4));
      m0 = fmaxf(m0, __shfl_xor(m0, 8));
      mnew[r]  = fmaxf(mrun[r], m0);
      alpha[r] = exp2f(mrun[r] - mnew[r]);
      mrun[r]  = mnew[r];
      lsum[r]  = 0.f;
    }
    #pragma unroll
    for (int kt = 0; kt < 4; ++kt)
      #pragma unroll
      for (int r = 0; r < 4; ++r) {
        float p = exp2f(s4[kt][r] - mnew[r]);
        lsum[r] += p;
        Plds[wid][(g * 4 + r) * 72 + kt * 16 + l15] = f2bf(p);
      }
    #pragma unroll
    for (int r = 0; r < 4; ++r) {
      lsum[r] += __shfl_xor(lsum[r], 1);
      lsum[r] += __shfl_xor(lsum[r], 2);
      lsum[r] += __shfl_xor(lsum[r], 4);
      lsum[r] += __shfl_xor(lsum[r], 8);
      lrun[r] = lrun[r] * alpha[r] + lsum[r];
    }
    #pragma unroll
    for (int nt = 0; nt < 4; ++nt) {
      o[nt][0] *= alpha[0]; o[nt][1] *= alpha[1];
      o[nt][2] *= alpha[2]; o[nt][3] *= alpha[3];
    }

    // P writes are wave-local: fence LDS, block compiler reordering
    asm volatile("s_waitcnt lgkmcnt(0)" ::: "memory");

    // ---- O += P V : A = P [16q x 32k], B = V^T-read [32k x 16d], 8 MFMA ----
    bf16x8 pa0 = *reinterpret_cast<const bf16x8*>(&Plds[wid][l15 * 72 + g * 8]);
    bf16x8 pa1 = *reinterpret_cast<const bf16x8*>(&Plds[wid][l15 * 72 + 32 + g * 8]);
    #pragma unroll
    for (int nt = 0; nt < 4; ++nt) {
      bf16x8 vf0 = *reinterpret_cast<const bf16x8*>(Vt + (nt * 16 + l15) * 72 + g * 8);
      o[nt] = __builtin_amdgcn_mfma_f32_16x16x32_bf16(pa0, vf0, o[nt], 0, 0, 0);
      bf16x8 vf1 = *reinterpret_cast<const bf16x8*>(Vt + (nt * 16 + l15) * 72 + 32 + g * 8);
      o[nt] = __builtin_amdgcn_mfma_f32_16x16x32_bf16(pa1, vf1, o[nt], 0, 0, 0);
    }
    __syncthreads();   // done with K/V/P of this tile before next staging
  }

  // ---- epilogue: O/l -> attn_out bf16 [B][N][C] ----
  const int b = bh >> 4, h = bh & 15;
  #pragma unroll
  for (int r = 0; r < 4; ++r) {
    float inv = 1.f / lrun[r];
    int n = q0 + wid * 16 + g * 4 + r;
    size_t base = ((size_t)(b * 1024) + n) * 1024 + h * 64;
    #pragma unroll
    for (int nt = 0; nt < 4; ++nt)
      aout[base + nt * 16 + l15] = f2bf(o[nt][r] * inv);
  }
}

// ---------------------------------------------------------------------------
extern "C" void kernel_launch(void* const* d_in, const int* in_sizes, int n_in,
                              void* d_out, int out_size, void* d_ws, size_t ws_size,
                              hipStream_t stream) {
  const float* x      = (const float*)d_in[0];   // [8,1024,1024]
  const float* ropef  = (const float*)d_in[1];   // [1,1024,1,64]
  const float* qkv_w  = (const float*)d_in[2];   // [3072,1024]
  const float* proj_w = (const float*)d_in[3];   // [1024,1024]
  const float* proj_b = (const float*)d_in[4];   // [1024]
  float* out = (float*)d_out;

  char* ws = (char*)d_ws;
  short*  xb  = (short*)(ws + 0);            // 16 MB  x bf16
  short*  wqb = (short*)(ws + 16777216);     //  6 MB  qkv_w bf16
  short*  wpb = (short*)(ws + 23068672);     //  2 MB  proj_w bf16
  short*  qb  = (short*)(ws + 25165824);     // 16 MB  q [bh][n][d]
  short*  kb  = (short*)(ws + 41943040);     // 16 MB  k
  short*  vb  = (short*)(ws + 58720256);     // 16 MB  v
  short*  aob = (short*)(ws + 75497472);     // 16 MB  attn out bf16 [B][N][C]
  float2* tbl = (float2*)(ws + 92274688);    // 512 KB cos/sin table
  // total ~88.5 MB of workspace

  cvt_bf16<<<8192, 256, 0, stream>>>(x, xb, 2097152);
  cvt_bf16<<<3072, 256, 0, stream>>>(qkv_w, wqb, 786432);
  cvt_bf16<<<1024, 256, 0, stream>>>(proj_w, wpb, 262144);
  rope_table<<<256, 256, 0, stream>>>(ropef, tbl);

  gemm_qkv_k<<<dim3(24, 64), 256, 0, stream>>>(xb, wqb, qb, kb, vb);
  rope_apply<<<16384, 256, 0, stream>>>(qb, kb, tbl);
  attn_kernel<<<dim3(16, 128), 256, 0, stream>>>(qb, kb, vb, aob);
  gemm_proj_k<<<dim3(8, 64), 256, 0, stream>>>(aob, wpb, proj_b, out);
}

// Round 2
// 217.770 us; speedup vs baseline: 1.2626x; 1.2626x over previous
//
#include <hip/hip_runtime.h>

// ---------------------------------------------------------------------------
// Fused attention block: qkv-proj(+RoPE fused) -> flash attention -> out-proj
// B=8 N=1024 C=1024 H=16 D=64.  All matmuls bf16 MFMA 16x16x32, fp32 acc.
// ---------------------------------------------------------------------------

typedef __attribute__((ext_vector_type(8))) short bf16x8;
typedef __attribute__((ext_vector_type(4))) float floatx4;
typedef __attribute__((ext_vector_type(4))) unsigned int u32x4;

__device__ __forceinline__ void gld16(const void* g, void* l) {
  __builtin_amdgcn_global_load_lds((const __attribute__((address_space(1))) void*)g,
                                   (__attribute__((address_space(3))) void*)l, 16, 0, 0);
}

__device__ __forceinline__ short f2bf(float f) {          // RNE fp32->bf16
  unsigned u = __builtin_bit_cast(unsigned, f);
  u = (u + 0x7FFFu + ((u >> 16) & 1u)) >> 16;
  return (short)u;
}
__device__ __forceinline__ unsigned packbf(float lo, float hi) {
  return (unsigned)(unsigned short)f2bf(lo) | ((unsigned)(unsigned short)f2bf(hi) << 16);
}

// ---------------- fp32 -> bf16 convert ----------------
__global__ __launch_bounds__(256) void cvt_bf16(const float* __restrict__ src,
                                                short* __restrict__ dst, int n4) {
  int i = blockIdx.x * 256 + threadIdx.x;
  if (i < n4) {
    float4 v = reinterpret_cast<const float4*>(src)[i];
    short4 o;
    o.x = f2bf(v.x); o.y = f2bf(v.y); o.z = f2bf(v.z); o.w = f2bf(v.w);
    reinterpret_cast<short4*>(dst)[i] = o;
  }
}

// ---------------- RoPE cos/sin table [N=1024][D=64] ----------------
__global__ __launch_bounds__(256) void rope_table(const float* __restrict__ f,
                                                  float2* __restrict__ tbl) {
  int i = blockIdx.x * 256 + threadIdx.x;   // 65536
  float v = f[i];
  tbl[i] = make_float2(cosf(v), sinf(v));
}

// scale (D^-0.5 = 1/8) * log2(e): softmax computed with exp2
#define QSCALE 0.18033688011112042f

// ---------------- GEMM core: C[128x128] = A[128xK] * B[128xK]^T, K=1024 ----------------
__device__ __forceinline__ void gemm_main(const short* __restrict__ A,
                                          const short* __restrict__ Bm,
                                          short* As, short* Bs,
                                          floatx4 (&acc)[4][4]) {
  const int tid = threadIdx.x;
  const int wid = tid >> 6, lane = tid & 63;
  const int g = lane >> 4, l15 = lane & 15;
  const int wr = wid >> 1, wc = wid & 1;
  const size_t trow = (size_t)blockIdx.y * 128, tcol = (size_t)blockIdx.x * 128;
  floatx4 zero = {0.f, 0.f, 0.f, 0.f};
  #pragma unroll
  for (int i = 0; i < 4; ++i)
    #pragma unroll
    for (int j = 0; j < 4; ++j) acc[i][j] = zero;

  for (int k0 = 0; k0 < 1024; k0 += 64) {
    #pragma unroll
    for (int i = 0; i < 4; ++i) {
      const int cb = (i * 4 + wid) * 64;
      const int c  = cb + lane;
      const int r  = c >> 3, s = c & 7;
      const int koff = k0 + ((s ^ (r & 7)) << 3);
      gld16(A  + (trow + r) * 1024 + koff, As + (size_t)cb * 8);
      gld16(Bm + (tcol + r) * 1024 + koff, Bs + (size_t)cb * 8);
    }
    __syncthreads();
    #pragma unroll
    for (int ks = 0; ks < 2; ++ks) {
      bf16x8 af[4], bfr[4];
      #pragma unroll
      for (int mi = 0; mi < 4; ++mi) {
        int row = wr * 64 + mi * 16 + l15;
        int ch  = (ks * 4 + g) ^ (row & 7);
        af[mi] = *reinterpret_cast<const bf16x8*>(As + row * 64 + ch * 8);
      }
      #pragma unroll
      for (int nt = 0; nt < 4; ++nt) {
        int row = wc * 64 + nt * 16 + l15;
        int ch  = (ks * 4 + g) ^ (row & 7);
        bfr[nt] = *reinterpret_cast<const bf16x8*>(Bs + row * 64 + ch * 8);
      }
      #pragma unroll
      for (int mi = 0; mi < 4; ++mi)
        #pragma unroll
        for (int nt = 0; nt < 4; ++nt)
          acc[mi][nt] = __builtin_amdgcn_mfma_f32_16x16x32_bf16(af[mi], bfr[nt],
                                                                acc[mi][nt], 0, 0, 0);
    }
    __syncthreads();
  }
}

// QKV GEMM with fused RoPE epilogue.  blockIdx.x: 0..7 -> q, 8..15 -> k, 16..23 -> v.
// q/k written [bh][n][d] with RoPE (q also pre-scaled); v written TRANSPOSED [bh][d][n].
__global__ __launch_bounds__(256) void gemm_qkv_k(const short* __restrict__ A,
                                                  const short* __restrict__ Bm,
                                                  const float2* __restrict__ tbl,
                                                  short* __restrict__ qo,
                                                  short* __restrict__ ko,
                                                  short* __restrict__ vt) {
  __shared__ __align__(16) short As[128 * 64];
  __shared__ __align__(16) short Bs[128 * 64];
  floatx4 acc[4][4];
  gemm_main(A, Bm, As, Bs, acc);

  const int tid = threadIdx.x;
  const int wid = tid >> 6, lane = tid & 63;
  const int g = lane >> 4, l15 = lane & 15;
  const int wr = wid >> 1, wc = wid & 1;
  const int trow = blockIdx.y * 128, tcol = blockIdx.x * 128;
  const int which = blockIdx.x >> 3;

  if (which < 2) {
    short* dst = which == 0 ? qo : ko;
    const float sc = which == 0 ? QSCALE : 1.0f;
    #pragma unroll
    for (int nt = 0; nt < 2; ++nt) {              // pairs (nt, nt+2) = (d, d+32)
      int col = tcol + wc * 64 + nt * 16 + l15;
      int hc = col & 1023, h = hc >> 6, d1 = hc & 63;   // d1 in [0,32)
      #pragma unroll
      for (int mi = 0; mi < 4; ++mi)
        #pragma unroll
        for (int r = 0; r < 4; ++r) {
          int rowg = trow + wr * 64 + mi * 16 + g * 4 + r;
          int b = rowg >> 10, n = rowg & 1023;
          float a1 = acc[mi][nt][r], a2 = acc[mi][nt + 2][r];
          float2 c1 = tbl[n * 64 + d1];
          float2 c2 = tbl[n * 64 + d1 + 32];
          float o1 = (a1 * c1.x - a2 * c1.y) * sc;
          float o2 = (a2 * c2.x + a1 * c2.y) * sc;
          size_t base = ((size_t)(b * 16 + h) * 1024 + n) * 64;
          dst[base + d1]      = f2bf(o1);
          dst[base + d1 + 32] = f2bf(o2);
        }
    }
  } else {
    // V^T [bh][d=64][n=1024]; acc reg axis r = consecutive n -> 8B packed stores
    #pragma unroll
    for (int nt = 0; nt < 4; ++nt) {
      int col = tcol + wc * 64 + nt * 16 + l15;
      int hc = col & 1023, h = hc >> 6, d = hc & 63;
      #pragma unroll
      for (int mi = 0; mi < 4; ++mi) {
        int rowg = trow + wr * 64 + mi * 16 + g * 4;
        int b = rowg >> 10, n0 = rowg & 1023;
        ushort4 pk;
        pk.x = (unsigned short)f2bf(acc[mi][nt][0]);
        pk.y = (unsigned short)f2bf(acc[mi][nt][1]);
        pk.z = (unsigned short)f2bf(acc[mi][nt][2]);
        pk.w = (unsigned short)f2bf(acc[mi][nt][3]);
        *reinterpret_cast<ushort4*>((unsigned short*)vt +
            ((size_t)(b * 16 + h) * 64 + d) * 1024 + n0) = pk;
      }
    }
  }
}

// Proj GEMM: attn_out bf16 [8192x1024] x proj_w bf16 [1024x1024]^T + bias -> fp32
__global__ __launch_bounds__(256) void gemm_proj_k(const short* __restrict__ A,
                                                   const short* __restrict__ Bm,
                                                   const float* __restrict__ pb,
                                                   float* __restrict__ out) {
  __shared__ __align__(16) short As[128 * 64];
  __shared__ __align__(16) short Bs[128 * 64];
  floatx4 acc[4][4];
  gemm_main(A, Bm, As, Bs, acc);

  const int tid = threadIdx.x;
  const int wid = tid >> 6, lane = tid & 63;
  const int g = lane >> 4, l15 = lane & 15;
  const int wr = wid >> 1, wc = wid & 1;
  const int trow = blockIdx.y * 128, tcol = blockIdx.x * 128;
  #pragma unroll
  for (int nt = 0; nt < 4; ++nt) {
    int col = tcol + wc * 64 + nt * 16 + l15;
    float bias = pb[col];
    #pragma unroll
    for (int mi = 0; mi < 4; ++mi)
      #pragma unroll
      for (int r = 0; r < 4; ++r) {
        int rowg = trow + wr * 64 + mi * 16 + g * 4 + r;
        out[(size_t)rowg * 1024 + col] = acc[mi][nt][r] + bias;
      }
  }
}

// ---------------- flash attention (swapped-QK^T, register softmax) ----------------
// grid (16 q-tiles, 128 bh); 4 waves x 16 q-rows.  KV tile 64, double-buffered.
// S^T = mfma(K,Q): lane (g,l15) owns q=l15, k = kt*16+4g+r  -> per-lane scalar m,l.
// P redistributed to PV A-fragments by an 8-op shfl_xor butterfly (no P_lds).
__global__ __launch_bounds__(256) void attn_kernel(const short* __restrict__ qs,
                                                   const short* __restrict__ ksrc,
                                                   const short* __restrict__ vt,
                                                   short* __restrict__ aout) {
  __shared__ __align__(16) short Kl[2][64 * 64];
  __shared__ __align__(16) short Vl[2][64 * 64];

  const int tid = threadIdx.x, wid = tid >> 6, lane = tid & 63;
  const int g = lane >> 4, l15 = lane & 15;
  const bool p5 = (lane & 32) != 0, p4 = (lane & 16) != 0;
  const int bh = blockIdx.y, q0 = blockIdx.x * 64;
  const size_t bhoff = (size_t)bh * 1024 * 64;
  const short* Kb = ksrc + bhoff;          // [n][d]
  const short* Vb = vt + bhoff;            // [d][n]

  const short* Qp = qs + bhoff + (size_t)(q0 + wid * 16 + l15) * 64 + g * 8;
  bf16x8 qf0 = *reinterpret_cast<const bf16x8*>(Qp);
  bf16x8 qf1 = *reinterpret_cast<const bf16x8*>(Qp + 32);

  floatx4 o[4];
  floatx4 zero = {0.f, 0.f, 0.f, 0.f};
  #pragma unroll
  for (int i = 0; i < 4; ++i) o[i] = zero;
  float mrun = -1e30f, lrun = 0.f;

  auto stage = [&](int buf, int t) {
    #pragma unroll
    for (int i = 0; i < 2; ++i) {
      const int cb = (i * 4 + wid) * 64;         // wave-uniform chunk base
      const int c = cb + lane;
      const int r = c >> 3, s = c & 7;
      const int off = (s ^ (r & 7)) << 3;        // pre-swizzled source
      gld16(Kb + (size_t)(t * 64 + r) * 64 + off, &Kl[buf][cb * 8]);
      gld16(Vb + (size_t)r * 1024 + t * 64 + off, &Vl[buf][cb * 8]);
    }
  };

  stage(0, 0);
  __syncthreads();

  for (int t = 0; t < 16; ++t) {
    const int buf = t & 1;
    if (t < 15) stage(buf ^ 1, t + 1);           // loads fly under compute

    // ---- S^T = K Q^T : D[k][q], 8 MFMA ----
    floatx4 s4[4];
    #pragma unroll
    for (int kt = 0; kt < 4; ++kt) s4[kt] = zero;
    #pragma unroll
    for (int kt = 0; kt < 4; ++kt) {
      int krow = kt * 16 + l15;
      int ch0 = (g ^ (krow & 7)) << 3, ch1 = (((4 + g)) ^ (krow & 7)) << 3;
      bf16x8 kf0 = *reinterpret_cast<const bf16x8*>(&Kl[buf][krow * 64 + ch0]);
      s4[kt] = __builtin_amdgcn_mfma_f32_16x16x32_bf16(kf0, qf0, s4[kt], 0, 0, 0);
      bf16x8 kf1 = *reinterpret_cast<const bf16x8*>(&Kl[buf][krow * 64 + ch1]);
      s4[kt] = __builtin_amdgcn_mfma_f32_16x16x32_bf16(kf1, qf1, s4[kt], 0, 0, 0);
    }

    // ---- per-lane online softmax (q = l15) ----
    float m0 = -1e30f;
    #pragma unroll
    for (int kt = 0; kt < 4; ++kt)
      m0 = fmaxf(m0, fmaxf(fmaxf(s4[kt][0], s4[kt][1]), fmaxf(s4[kt][2], s4[kt][3])));
    m0 = fmaxf(m0, __shfl_xor(m0, 16));
    m0 = fmaxf(m0, __shfl_xor(m0, 32));
    float mnew = fmaxf(mrun, m0);
    float alpha = exp2f(mrun - mnew);
    mrun = mnew;

    float p[4][4], lsum = 0.f;
    #pragma unroll
    for (int kt = 0; kt < 4; ++kt)
      #pragma unroll
      for (int r = 0; r < 4; ++r) {
        p[kt][r] = exp2f(s4[kt][r] - mnew);
        lsum += p[kt][r];
      }
    lsum += __shfl_xor(lsum, 16);
    lsum += __shfl_xor(lsum, 32);
    lrun = lrun * alpha + lsum;

    // ---- pack P to bf16 pairs: w[kt][h] covers k = kt*16+4g+2h+{0,1} ----
    unsigned w[4][2];
    #pragma unroll
    for (int kt = 0; kt < 4; ++kt) {
      w[kt][0] = packbf(p[kt][0], p[kt][1]);
      w[kt][1] = packbf(p[kt][2], p[kt][3]);
    }

    // ---- butterfly: dest word [ks][b][h] = src(lane gs=(2g+b)&3, word kt=2ks+g1, h)
    // stage 1: swap lane-bit p5 <-> word-bit kt0 (shfl_xor 32)
    // stage 2: swap lane-bit p4 <-> word-bit j   (shfl_xor 16)
    unsigned W[2][2][2];
    #pragma unroll
    for (int ks = 0; ks < 2; ++ks)
      #pragma unroll
      for (int h = 0; h < 2; ++h) {
        unsigned sup = p5 ? w[2 * ks][h] : w[2 * ks + 1][h];
        unsigned tx  = __shfl_xor((int)sup, 32);
        unsigned Y0  = p5 ? tx : w[2 * ks][h];
        unsigned Y1  = p5 ? w[2 * ks + 1][h] : tx;
        unsigned sup2 = p4 ? Y0 : Y1;
        unsigned t2   = __shfl_xor((int)sup2, 16);
        W[ks][0][h] = p4 ? t2 : Y0;
        W[ks][1][h] = p4 ? Y1 : t2;
      }
    u32x4 aw0 = {W[0][0][0], W[0][0][1], W[0][1][0], W[0][1][1]};
    u32x4 aw1 = {W[1][0][0], W[1][0][1], W[1][1][0], W[1][1][1]};
    bf16x8 pa0 = __builtin_bit_cast(bf16x8, aw0);
    bf16x8 pa1 = __builtin_bit_cast(bf16x8, aw1);

    // ---- rescale O: alpha for q = 4g+r lives at lanes with l15 = 4g+r ----
    const int slb = (lane & 48) + ((lane >> 4) << 2);
    float a4[4];
    #pragma unroll
    for (int r = 0; r < 4; ++r) a4[r] = __shfl(alpha, slb + r);
    #pragma unroll
    for (int nt = 0; nt < 4; ++nt) {
      o[nt][0] *= a4[0]; o[nt][1] *= a4[1]; o[nt][2] *= a4[2]; o[nt][3] *= a4[3];
    }

    // ---- O += P V : B = V^T rows (d), 8 MFMA ----
    #pragma unroll
    for (int nt = 0; nt < 4; ++nt) {
      int row = nt * 16 + l15;
      int ch0 = (g ^ (row & 7)) << 3, ch1 = ((4 + g) ^ (row & 7)) << 3;
      bf16x8 vf0 = *reinterpret_cast<const bf16x8*>(&Vl[buf][row * 64 + ch0]);
      o[nt] = __builtin_amdgcn_mfma_f32_16x16x32_bf16(pa0, vf0, o[nt], 0, 0, 0);
      bf16x8 vf1 = *reinterpret_cast<const bf16x8*>(&Vl[buf][row * 64 + ch1]);
      o[nt] = __builtin_amdgcn_mfma_f32_16x16x32_bf16(pa1, vf1, o[nt], 0, 0, 0);
    }
    __syncthreads();   // staged t+1 complete (barrier drains vmcnt); buf reusable
  }

  // ---- epilogue: O/l -> attn_out bf16 [B][N][C];  row q = 4g+r, col d = nt*16+l15
  const int b = bh >> 4, h = bh & 15;
  const int slb = (lane & 48) + ((lane >> 4) << 2);
  float inv = 1.f / lrun;
  #pragma unroll
  for (int r = 0; r < 4; ++r) {
    float ir = __shfl(inv, slb + r);
    int n = q0 + wid * 16 + g * 4 + r;
    size_t base = ((size_t)(b * 1024) + n) * 1024 + h * 64;
    #pragma unroll
    for (int nt = 0; nt < 4; ++nt)
      aout[base + nt * 16 + l15] = f2bf(o[nt][r] * ir);
  }
}

// ---------------------------------------------------------------------------
extern "C" void kernel_launch(void* const* d_in, const int* in_sizes, int n_in,
                              void* d_out, int out_size, void* d_ws, size_t ws_size,
                              hipStream_t stream) {
  const float* x      = (const float*)d_in[0];   // [8,1024,1024]
  const float* ropef  = (const float*)d_in[1];   // [1,1024,1,64]
  const float* qkv_w  = (const float*)d_in[2];   // [3072,1024]
  const float* proj_w = (const float*)d_in[3];   // [1024,1024]
  const float* proj_b = (const float*)d_in[4];   // [1024]
  float* out = (float*)d_out;

  char* ws = (char*)d_ws;
  short*  xb  = (short*)(ws + 0);            // 16 MB  x bf16
  short*  wqb = (short*)(ws + 16777216);     //  6 MB  qkv_w bf16
  short*  wpb = (short*)(ws + 23068672);     //  2 MB  proj_w bf16
  short*  qb  = (short*)(ws + 25165824);     // 16 MB  q [bh][n][d] (RoPE+scale)
  short*  kb  = (short*)(ws + 41943040);     // 16 MB  k [bh][n][d] (RoPE)
  short*  vtb = (short*)(ws + 58720256);     // 16 MB  v^T [bh][d][n]
  short*  aob = (short*)(ws + 75497472);     // 16 MB  attn out bf16 [B][N][C]
  float2* tbl = (float2*)(ws + 92274688);    // 512 KB cos/sin table

  cvt_bf16<<<8192, 256, 0, stream>>>(x, xb, 2097152);
  cvt_bf16<<<3072, 256, 0, stream>>>(qkv_w, wqb, 786432);
  cvt_bf16<<<1024, 256, 0, stream>>>(proj_w, wpb, 262144);
  rope_table<<<256, 256, 0, stream>>>(ropef, tbl);

  gemm_qkv_k<<<dim3(24, 64), 256, 0, stream>>>(xb, wqb, tbl, qb, kb, vtb);
  attn_kernel<<<dim3(16, 128), 256, 0, stream>>>(qb, kb, vtb, aob);
  gemm_proj_k<<<dim3(8, 64), 256, 0, stream>>>(aob, wpb, proj_b, out);
}

// Round 3
// 200.394 us; speedup vs baseline: 1.3721x; 1.0867x over previous
//
#include <hip/hip_runtime.h>

// ---------------------------------------------------------------------------
// Fused attention block: qkv-proj(+RoPE fused) -> flash attention -> out-proj
// B=8 N=1024 C=1024 H=16 D=64.  All matmuls bf16 MFMA 16x16x32, fp32 acc.
// ---------------------------------------------------------------------------

typedef __attribute__((ext_vector_type(8))) short bf16x8;
typedef __attribute__((ext_vector_type(4))) float floatx4;
typedef __attribute__((ext_vector_type(4))) unsigned int u32x4;
typedef __attribute__((ext_vector_type(2))) unsigned int u32x2;

__device__ __forceinline__ void gld16(const void* g, void* l) {
  __builtin_amdgcn_global_load_lds((const __attribute__((address_space(1))) void*)g,
                                   (__attribute__((address_space(3))) void*)l, 16, 0, 0);
}

__device__ __forceinline__ short f2bf(float f) {          // RNE fp32->bf16
  unsigned u = __builtin_bit_cast(unsigned, f);
  u = (u + 0x7FFFu + ((u >> 16) & 1u)) >> 16;
  return (short)u;
}
__device__ __forceinline__ unsigned cvtpk(float lo, float hi) {
  unsigned r;
  asm("v_cvt_pk_bf16_f32 %0, %1, %2" : "=v"(r) : "v"(lo), "v"(hi));
  return r;
}

// ---------------- fp32 -> bf16 convert ----------------
__global__ __launch_bounds__(256) void cvt_bf16(const float* __restrict__ src,
                                                short* __restrict__ dst, int n4) {
  int i = blockIdx.x * 256 + threadIdx.x;
  if (i < n4) {
    float4 v = reinterpret_cast<const float4*>(src)[i];
    short4 o;
    o.x = f2bf(v.x); o.y = f2bf(v.y); o.z = f2bf(v.z); o.w = f2bf(v.w);
    reinterpret_cast<short4*>(dst)[i] = o;
  }
}

// ---------------- RoPE cos/sin table [N=1024][D=64] ----------------
__global__ __launch_bounds__(256) void rope_table(const float* __restrict__ f,
                                                  float2* __restrict__ tbl) {
  int i = blockIdx.x * 256 + threadIdx.x;   // 65536
  float v = f[i];
  tbl[i] = make_float2(cosf(v), sinf(v));
}

// scale (D^-0.5 = 1/8) * log2(e): softmax computed with exp2
#define QSCALE 0.18033688011112042f

// ---------------- GEMM core: C[128x128] = A[128xK] * B[128xK]^T, K=1024 ----------------
__device__ __forceinline__ void gemm_main(const short* __restrict__ A,
                                          const short* __restrict__ Bm,
                                          short* As, short* Bs,
                                          floatx4 (&acc)[4][4]) {
  const int tid = threadIdx.x;
  const int wid = tid >> 6, lane = tid & 63;
  const int g = lane >> 4, l15 = lane & 15;
  const int wr = wid >> 1, wc = wid & 1;
  const size_t trow = (size_t)blockIdx.y * 128, tcol = (size_t)blockIdx.x * 128;
  floatx4 zero = {0.f, 0.f, 0.f, 0.f};
  #pragma unroll
  for (int i = 0; i < 4; ++i)
    #pragma unroll
    for (int j = 0; j < 4; ++j) acc[i][j] = zero;

  for (int k0 = 0; k0 < 1024; k0 += 64) {
    #pragma unroll
    for (int i = 0; i < 4; ++i) {
      const int cb = (i * 4 + wid) * 64;
      const int c  = cb + lane;
      const int r  = c >> 3, s = c & 7;
      const int koff = k0 + ((s ^ (r & 7)) << 3);
      gld16(A  + (trow + r) * 1024 + koff, As + (size_t)cb * 8);
      gld16(Bm + (tcol + r) * 1024 + koff, Bs + (size_t)cb * 8);
    }
    __syncthreads();
    #pragma unroll
    for (int ks = 0; ks < 2; ++ks) {
      bf16x8 af[4], bfr[4];
      #pragma unroll
      for (int mi = 0; mi < 4; ++mi) {
        int row = wr * 64 + mi * 16 + l15;
        int ch  = (ks * 4 + g) ^ (row & 7);
        af[mi] = *reinterpret_cast<const bf16x8*>(As + row * 64 + ch * 8);
      }
      #pragma unroll
      for (int nt = 0; nt < 4; ++nt) {
        int row = wc * 64 + nt * 16 + l15;
        int ch  = (ks * 4 + g) ^ (row & 7);
        bfr[nt] = *reinterpret_cast<const bf16x8*>(Bs + row * 64 + ch * 8);
      }
      #pragma unroll
      for (int mi = 0; mi < 4; ++mi)
        #pragma unroll
        for (int nt = 0; nt < 4; ++nt)
          acc[mi][nt] = __builtin_amdgcn_mfma_f32_16x16x32_bf16(af[mi], bfr[nt],
                                                                acc[mi][nt], 0, 0, 0);
    }
    __syncthreads();
  }
}

// QKV GEMM with fused RoPE epilogue.  blockIdx.x: 0..7 -> q, 8..15 -> k, 16..23 -> v.
// q/k written [bh][n][d] with RoPE (q also pre-scaled); v written TRANSPOSED [bh][d][n].
__global__ __launch_bounds__(256) void gemm_qkv_k(const short* __restrict__ A,
                                                  const short* __restrict__ Bm,
                                                  const float2* __restrict__ tbl,
                                                  short* __restrict__ qo,
                                                  short* __restrict__ ko,
                                                  short* __restrict__ vt) {
  __shared__ __align__(16) short As[128 * 64];
  __shared__ __align__(16) short Bs[128 * 64];
  floatx4 acc[4][4];
  gemm_main(A, Bm, As, Bs, acc);

  const int tid = threadIdx.x;
  const int wid = tid >> 6, lane = tid & 63;
  const int g = lane >> 4, l15 = lane & 15;
  const int wr = wid >> 1, wc = wid & 1;
  const int trow = blockIdx.y * 128, tcol = blockIdx.x * 128;
  const int which = blockIdx.x >> 3;

  if (which < 2) {
    short* dst = which == 0 ? qo : ko;
    const float sc = which == 0 ? QSCALE : 1.0f;
    #pragma unroll
    for (int nt = 0; nt < 2; ++nt) {              // pairs (nt, nt+2) = (d, d+32)
      int col = tcol + wc * 64 + nt * 16 + l15;
      int hc = col & 1023, h = hc >> 6, d1 = hc & 63;   // d1 in [0,32)
      #pragma unroll
      for (int mi = 0; mi < 4; ++mi)
        #pragma unroll
        for (int r = 0; r < 4; ++r) {
          int rowg = trow + wr * 64 + mi * 16 + g * 4 + r;
          int b = rowg >> 10, n = rowg & 1023;
          float a1 = acc[mi][nt][r], a2 = acc[mi][nt + 2][r];
          float2 c1 = tbl[n * 64 + d1];
          float2 c2 = tbl[n * 64 + d1 + 32];
          float o1 = (a1 * c1.x - a2 * c1.y) * sc;
          float o2 = (a2 * c2.x + a1 * c2.y) * sc;
          size_t base = ((size_t)(b * 16 + h) * 1024 + n) * 64;
          dst[base + d1]      = f2bf(o1);
          dst[base + d1 + 32] = f2bf(o2);
        }
    }
  } else {
    // V^T [bh][d=64][n=1024]; acc reg axis r = consecutive n -> 8B packed stores
    #pragma unroll
    for (int nt = 0; nt < 4; ++nt) {
      int col = tcol + wc * 64 + nt * 16 + l15;
      int hc = col & 1023, h = hc >> 6, d = hc & 63;
      #pragma unroll
      for (int mi = 0; mi < 4; ++mi) {
        int rowg = trow + wr * 64 + mi * 16 + g * 4;
        int b = rowg >> 10, n0 = rowg & 1023;
        ushort4 pk;
        pk.x = (unsigned short)f2bf(acc[mi][nt][0]);
        pk.y = (unsigned short)f2bf(acc[mi][nt][1]);
        pk.z = (unsigned short)f2bf(acc[mi][nt][2]);
        pk.w = (unsigned short)f2bf(acc[mi][nt][3]);
        *reinterpret_cast<ushort4*>((unsigned short*)vt +
            ((size_t)(b * 16 + h) * 64 + d) * 1024 + n0) = pk;
      }
    }
  }
}

// Proj GEMM: attn_out bf16 [8192x1024] x proj_w bf16 [1024x1024]^T + bias -> fp32
__global__ __launch_bounds__(256) void gemm_proj_k(const short* __restrict__ A,
                                                   const short* __restrict__ Bm,
                                                   const float* __restrict__ pb,
                                                   float* __restrict__ out) {
  __shared__ __align__(16) short As[128 * 64];
  __shared__ __align__(16) short Bs[128 * 64];
  floatx4 acc[4][4];
  gemm_main(A, Bm, As, Bs, acc);

  const int tid = threadIdx.x;
  const int wid = tid >> 6, lane = tid & 63;
  const int g = lane >> 4, l15 = lane & 15;
  const int wr = wid >> 1, wc = wid & 1;
  const int trow = blockIdx.y * 128, tcol = blockIdx.x * 128;
  #pragma unroll
  for (int nt = 0; nt < 4; ++nt) {
    int col = tcol + wc * 64 + nt * 16 + l15;
    float bias = pb[col];
    #pragma unroll
    for (int mi = 0; mi < 4; ++mi)
      #pragma unroll
      for (int r = 0; r < 4; ++r) {
        int rowg = trow + wr * 64 + mi * 16 + g * 4 + r;
        out[(size_t)rowg * 1024 + col] = acc[mi][nt][r] + bias;
      }
  }
}

// ---------------- flash attention (swapped-QK^T, register softmax) ----------------
// grid (16 q-tiles, 128 bh); 4 waves x 16 q-rows.  KV tile 64, double-buffered.
// S^T = mfma(K,Q): lane (g,l15) owns q=l15, k = kt*16+4g+r -> per-lane scalar m,l.
// P redistribution: 4x permlane32_swap + 4x permlane16_swap (verified identical
// dataflow to the previously-passing shfl_xor butterfly).
__global__ __launch_bounds__(256) void attn_kernel(const short* __restrict__ qs,
                                                   const short* __restrict__ ksrc,
                                                   const short* __restrict__ vt,
                                                   short* __restrict__ aout) {
  __shared__ __align__(16) short Kl[2][64 * 64];
  __shared__ __align__(16) short Vl[2][64 * 64];

  const int tid = threadIdx.x, wid = tid >> 6, lane = tid & 63;
  const int g = lane >> 4, l15 = lane & 15;
  const int bh = blockIdx.y, q0 = blockIdx.x * 64;
  const size_t bhoff = (size_t)bh * 1024 * 64;
  const short* Kb = ksrc + bhoff;          // [n][d]
  const short* Vb = vt + bhoff;            // [d][n]

  const short* Qp = qs + bhoff + (size_t)(q0 + wid * 16 + l15) * 64 + g * 8;
  bf16x8 qf0 = *reinterpret_cast<const bf16x8*>(Qp);
  bf16x8 qf1 = *reinterpret_cast<const bf16x8*>(Qp + 32);

  floatx4 o[4];
  floatx4 zero = {0.f, 0.f, 0.f, 0.f};
  #pragma unroll
  for (int i = 0; i < 4; ++i) o[i] = zero;
  float mrun = -1e30f, lrun = 0.f;

  auto stage = [&](int buf, int t) {
    #pragma unroll
    for (int i = 0; i < 2; ++i) {
      const int cb = (i * 4 + wid) * 64;         // wave-uniform chunk base
      const int c = cb + lane;
      const int r = c >> 3, s = c & 7;
      const int off = (s ^ (r & 7)) << 3;        // pre-swizzled source
      gld16(Kb + (size_t)(t * 64 + r) * 64 + off, &Kl[buf][cb * 8]);
      gld16(Vb + (size_t)r * 1024 + t * 64 + off, &Vl[buf][cb * 8]);
    }
  };

  stage(0, 0);
  __syncthreads();

  for (int t = 0; t < 16; ++t) {
    const int buf = t & 1;
    if (t < 15) stage(buf ^ 1, t + 1);           // loads fly under compute

    // ---- S^T = K Q^T : D[k][q], 8 MFMA ----
    floatx4 s4[4];
    #pragma unroll
    for (int kt = 0; kt < 4; ++kt) s4[kt] = zero;
    __builtin_amdgcn_s_setprio(1);
    #pragma unroll
    for (int kt = 0; kt < 4; ++kt) {
      int krow = kt * 16 + l15;
      int ch0 = (g ^ (krow & 7)) << 3, ch1 = (((4 + g)) ^ (krow & 7)) << 3;
      bf16x8 kf0 = *reinterpret_cast<const bf16x8*>(&Kl[buf][krow * 64 + ch0]);
      s4[kt] = __builtin_amdgcn_mfma_f32_16x16x32_bf16(kf0, qf0, s4[kt], 0, 0, 0);
      bf16x8 kf1 = *reinterpret_cast<const bf16x8*>(&Kl[buf][krow * 64 + ch1]);
      s4[kt] = __builtin_amdgcn_mfma_f32_16x16x32_bf16(kf1, qf1, s4[kt], 0, 0, 0);
    }
    __builtin_amdgcn_s_setprio(0);

    // ---- per-lane online softmax (q = l15), defer-max (THR=8 in exp2 dom) ----
    float m0 = -1e30f;
    #pragma unroll
    for (int kt = 0; kt < 4; ++kt)
      m0 = fmaxf(m0, fmaxf(fmaxf(s4[kt][0], s4[kt][1]), fmaxf(s4[kt][2], s4[kt][3])));
    m0 = fmaxf(m0, __shfl_xor(m0, 16));
    m0 = fmaxf(m0, __shfl_xor(m0, 32));

    if (!__all(m0 - mrun <= 8.f)) {
      float mnew = fmaxf(mrun, m0);
      float alpha = exp2f(mrun - mnew);
      mrun = mnew;
      lrun *= alpha;
      const int slb = (lane & 48) + ((lane >> 4) << 2);
      float a4[4];
      #pragma unroll
      for (int r = 0; r < 4; ++r) a4[r] = __shfl(alpha, slb + r);
      #pragma unroll
      for (int nt = 0; nt < 4; ++nt) {
        o[nt][0] *= a4[0]; o[nt][1] *= a4[1]; o[nt][2] *= a4[2]; o[nt][3] *= a4[3];
      }
    }

    float p[4][4], lsum = 0.f;
    #pragma unroll
    for (int kt = 0; kt < 4; ++kt)
      #pragma unroll
      for (int r = 0; r < 4; ++r) {
        p[kt][r] = exp2f(s4[kt][r] - mrun);
        lsum += p[kt][r];
      }
    lsum += __shfl_xor(lsum, 16);
    lsum += __shfl_xor(lsum, 32);
    lrun += lsum;

    // ---- pack P to bf16 pairs: w[kt][h] covers k = kt*16+4g+2h+{0,1} ----
    unsigned w[4][2];
    #pragma unroll
    for (int kt = 0; kt < 4; ++kt) {
      w[kt][0] = cvtpk(p[kt][0], p[kt][1]);
      w[kt][1] = cvtpk(p[kt][2], p[kt][3]);
    }

    // ---- butterfly via permlane swaps: dest W[ks][b][h] ----
    unsigned W[2][2][2];
    #pragma unroll
    for (int ks = 0; ks < 2; ++ks)
      #pragma unroll
      for (int h = 0; h < 2; ++h) {
        u32x2 y = __builtin_amdgcn_permlane32_swap(w[2 * ks][h], w[2 * ks + 1][h],
                                                   false, false);
        u32x2 z = __builtin_amdgcn_permlane16_swap(y[0], y[1], false, false);
        W[ks][0][h] = z[0];
        W[ks][1][h] = z[1];
      }
    u32x4 aw0 = {W[0][0][0], W[0][0][1], W[0][1][0], W[0][1][1]};
    u32x4 aw1 = {W[1][0][0], W[1][0][1], W[1][1][0], W[1][1][1]};
    bf16x8 pa0 = __builtin_bit_cast(bf16x8, aw0);
    bf16x8 pa1 = __builtin_bit_cast(bf16x8, aw1);

    // ---- O += P V : B = V^T rows (d), 8 MFMA ----
    __builtin_amdgcn_s_setprio(1);
    #pragma unroll
    for (int nt = 0; nt < 4; ++nt) {
      int row = nt * 16 + l15;
      int ch0 = (g ^ (row & 7)) << 3, ch1 = ((4 + g) ^ (row & 7)) << 3;
      bf16x8 vf0 = *reinterpret_cast<const bf16x8*>(&Vl[buf][row * 64 + ch0]);
      o[nt] = __builtin_amdgcn_mfma_f32_16x16x32_bf16(pa0, vf0, o[nt], 0, 0, 0);
      bf16x8 vf1 = *reinterpret_cast<const bf16x8*>(&Vl[buf][row * 64 + ch1]);
      o[nt] = __builtin_amdgcn_mfma_f32_16x16x32_bf16(pa1, vf1, o[nt], 0, 0, 0);
    }
    __builtin_amdgcn_s_setprio(0);
    __syncthreads();   // staged t+1 complete (barrier drains vmcnt); buf reusable
  }

  // ---- epilogue: O/l -> attn_out bf16 [B][N][C];  row q = 4g+r, col d = nt*16+l15
  const int b = bh >> 4, h = bh & 15;
  const int slb = (lane & 48) + ((lane >> 4) << 2);
  float inv = 1.f / lrun;
  #pragma unroll
  for (int r = 0; r < 4; ++r) {
    float ir = __shfl(inv, slb + r);
    int n = q0 + wid * 16 + g * 4 + r;
    size_t base = ((size_t)(b * 1024) + n) * 1024 + h * 64;
    #pragma unroll
    for (int nt = 0; nt < 4; ++nt)
      aout[base + nt * 16 + l15] = f2bf(o[nt][r] * ir);
  }
}

// ---------------------------------------------------------------------------
extern "C" void kernel_launch(void* const* d_in, const int* in_sizes, int n_in,
                              void* d_out, int out_size, void* d_ws, size_t ws_size,
                              hipStream_t stream) {
  const float* x      = (const float*)d_in[0];   // [8,1024,1024]
  const float* ropef  = (const float*)d_in[1];   // [1,1024,1,64]
  const float* qkv_w  = (const float*)d_in[2];   // [3072,1024]
  const float* proj_w = (const float*)d_in[3];   // [1024,1024]
  const float* proj_b = (const float*)d_in[4];   // [1024]
  float* out = (float*)d_out;

  char* ws = (char*)d_ws;
  short*  xb  = (short*)(ws + 0);            // 16 MB  x bf16
  short*  wqb = (short*)(ws + 16777216);     //  6 MB  qkv_w bf16
  short*  wpb = (short*)(ws + 23068672);     //  2 MB  proj_w bf16
  short*  qb  = (short*)(ws + 25165824);     // 16 MB  q [bh][n][d] (RoPE+scale)
  short*  kb  = (short*)(ws + 41943040);     // 16 MB  k [bh][n][d] (RoPE)
  short*  vtb = (short*)(ws + 58720256);     // 16 MB  v^T [bh][d][n]
  short*  aob = (short*)(ws + 75497472);     // 16 MB  attn out bf16 [B][N][C]
  float2* tbl = (float2*)(ws + 92274688);    // 512 KB cos/sin table

  cvt_bf16<<<8192, 256, 0, stream>>>(x, xb, 2097152);
  cvt_bf16<<<3072, 256, 0, stream>>>(qkv_w, wqb, 786432);
  cvt_bf16<<<1024, 256, 0, stream>>>(proj_w, wpb, 262144);
  rope_table<<<256, 256, 0, stream>>>(ropef, tbl);

  gemm_qkv_k<<<dim3(24, 64), 256, 0, stream>>>(xb, wqb, tbl, qb, kb, vtb);
  attn_kernel<<<dim3(16, 128), 256, 0, stream>>>(qb, kb, vtb, aob);
  gemm_proj_k<<<dim3(8, 64), 256, 0, stream>>>(aob, wpb, proj_b, out);
}

// Round 6
// 194.194 us; speedup vs baseline: 1.4159x; 1.0319x over previous
//
#include <hip/hip_runtime.h>

// ---------------------------------------------------------------------------
// Fused attention block: qkv-proj(+RoPE fused) -> flash attention -> out-proj
// B=8 N=1024 C=1024 H=16 D=64.  All matmuls bf16 MFMA 16x16x32, fp32 acc.
// ---------------------------------------------------------------------------

typedef __attribute__((ext_vector_type(8))) short bf16x8;
typedef __attribute__((ext_vector_type(4))) float floatx4;
typedef __attribute__((ext_vector_type(4))) unsigned int u32x4;
typedef __attribute__((ext_vector_type(2))) unsigned int u32x2;

__device__ __forceinline__ void gld16(const void* g, void* l) {
  __builtin_amdgcn_global_load_lds((const __attribute__((address_space(1))) void*)g,
                                   (__attribute__((address_space(3))) void*)l, 16, 0, 0);
}

__device__ __forceinline__ short f2bf(float f) {          // RNE fp32->bf16
  unsigned u = __builtin_bit_cast(unsigned, f);
  u = (u + 0x7FFFu + ((u >> 16) & 1u)) >> 16;
  return (short)u;
}
__device__ __forceinline__ unsigned cvtpk(float lo, float hi) {
  unsigned r;
  asm("v_cvt_pk_bf16_f32 %0, %1, %2" : "=v"(r) : "v"(lo), "v"(hi));
  return r;
}

// ---------------- fp32 -> bf16 convert (merged: x, qkv_w, proj_w) ----------------
// dst is one contiguous bf16 region (xb|wqb|wpb).  n4 = total float4 count.
__global__ __launch_bounds__(256) void cvt_bf16_all(const float* __restrict__ sx,
                                                    const float* __restrict__ sq,
                                                    const float* __restrict__ sp,
                                                    short* __restrict__ dst) {
  int i = blockIdx.x * 256 + threadIdx.x;     // 0 .. 3145728-1
  const float4* src;
  if (i < 2097152)      src = reinterpret_cast<const float4*>(sx) + i;
  else if (i < 2883584) src = reinterpret_cast<const float4*>(sq) + (i - 2097152);
  else                  src = reinterpret_cast<const float4*>(sp) + (i - 2883584);
  float4 v = *src;
  short4 o;
  o.x = f2bf(v.x); o.y = f2bf(v.y); o.z = f2bf(v.z); o.w = f2bf(v.w);
  reinterpret_cast<short4*>(dst)[i] = o;
}

// ---------------- RoPE cos/sin table [N=1024][D=64] ----------------
__global__ __launch_bounds__(256) void rope_table(const float* __restrict__ f,
                                                  float2* __restrict__ tbl) {
  int i = blockIdx.x * 256 + threadIdx.x;   // 65536
  float v = f[i];
  tbl[i] = make_float2(cosf(v), sinf(v));
}

// scale (D^-0.5 = 1/8) * log2(e): softmax computed with exp2
#define QSCALE 0.18033688011112042f

// ---------------- GEMM core: C[128x128] = A[128xK] * B[128xK]^T, K=1024 ----------------
// Tile coords (bx, by) passed in (XCD-swizzled by caller).
__device__ __forceinline__ void gemm_main(const short* __restrict__ A,
                                          const short* __restrict__ Bm,
                                          short* As, short* Bs,
                                          floatx4 (&acc)[4][4],
                                          int bx, int by) {
  const int tid = threadIdx.x;
  const int wid = tid >> 6, lane = tid & 63;
  const int g = lane >> 4, l15 = lane & 15;
  const int wr = wid >> 1, wc = wid & 1;
  const size_t trow = (size_t)by * 128, tcol = (size_t)bx * 128;
  floatx4 zero = {0.f, 0.f, 0.f, 0.f};
  #pragma unroll
  for (int i = 0; i < 4; ++i)
    #pragma unroll
    for (int j = 0; j < 4; ++j) acc[i][j] = zero;

  for (int k0 = 0; k0 < 1024; k0 += 64) {
    #pragma unroll
    for (int i = 0; i < 4; ++i) {
      const int cb = (i * 4 + wid) * 64;
      const int c  = cb + lane;
      const int r  = c >> 3, s = c & 7;
      const int koff = k0 + ((s ^ (r & 7)) << 3);
      gld16(A  + (trow + r) * 1024 + koff, As + (size_t)cb * 8);
      gld16(Bm + (tcol + r) * 1024 + koff, Bs + (size_t)cb * 8);
    }
    __syncthreads();
    #pragma unroll
    for (int ks = 0; ks < 2; ++ks) {
      bf16x8 af[4], bfr[4];
      #pragma unroll
      for (int mi = 0; mi < 4; ++mi) {
        int row = wr * 64 + mi * 16 + l15;
        int ch  = (ks * 4 + g) ^ (row & 7);
        af[mi] = *reinterpret_cast<const bf16x8*>(As + row * 64 + ch * 8);
      }
      #pragma unroll
      for (int nt = 0; nt < 4; ++nt) {
        int row = wc * 64 + nt * 16 + l15;
        int ch  = (ks * 4 + g) ^ (row & 7);
        bfr[nt] = *reinterpret_cast<const bf16x8*>(Bs + row * 64 + ch * 8);
      }
      #pragma unroll
      for (int mi = 0; mi < 4; ++mi)
        #pragma unroll
        for (int nt = 0; nt < 4; ++nt)
          acc[mi][nt] = __builtin_amdgcn_mfma_f32_16x16x32_bf16(af[mi], bfr[nt],
                                                                acc[mi][nt], 0, 0, 0);
    }
    __syncthreads();
  }
}

// QKV GEMM with fused RoPE epilogue.  bx: 0..7 -> q, 8..15 -> k, 16..23 -> v.
// q/k written [bh][n][d] with RoPE (q also pre-scaled); v written TRANSPOSED [bh][d][n].
__global__ __launch_bounds__(256) void gemm_qkv_k(const short* __restrict__ A,
                                                  const short* __restrict__ Bm,
                                                  const float2* __restrict__ tbl,
                                                  short* __restrict__ qo,
                                                  short* __restrict__ ko,
                                                  short* __restrict__ vt) {
  __shared__ __align__(16) short As[128 * 64];
  __shared__ __align__(16) short Bs[128 * 64];
  // XCD-aware bijective swizzle: nwg = 24*64 = 1536, 1536 % 8 == 0.
  const int id  = blockIdx.y * 24 + blockIdx.x;
  const int sid = (id & 7) * 192 + (id >> 3);
  const int bx  = sid % 24, by = sid / 24;
  floatx4 acc[4][4];
  gemm_main(A, Bm, As, Bs, acc, bx, by);

  const int tid = threadIdx.x;
  const int wid = tid >> 6, lane = tid & 63;
  const int g = lane >> 4, l15 = lane & 15;
  const int wr = wid >> 1, wc = wid & 1;
  const int trow = by * 128, tcol = bx * 128;
  const int which = bx >> 3;

  if (which < 2) {
    short* dst = which == 0 ? qo : ko;
    const float sc = which == 0 ? QSCALE : 1.0f;
    #pragma unroll
    for (int nt = 0; nt < 2; ++nt) {              // pairs (nt, nt+2) = (d, d+32)
      int col = tcol + wc * 64 + nt * 16 + l15;
      int hc = col & 1023, h = hc >> 6, d1 = hc & 63;   // d1 in [0,32)
      #pragma unroll
      for (int mi = 0; mi < 4; ++mi)
        #pragma unroll
        for (int r = 0; r < 4; ++r) {
          int rowg = trow + wr * 64 + mi * 16 + g * 4 + r;
          int b = rowg >> 10, n = rowg & 1023;
          float a1 = acc[mi][nt][r], a2 = acc[mi][nt + 2][r];
          float2 c1 = tbl[n * 64 + d1];
          float2 c2 = tbl[n * 64 + d1 + 32];
          float o1 = (a1 * c1.x - a2 * c1.y) * sc;
          float o2 = (a2 * c2.x + a1 * c2.y) * sc;
          size_t base = ((size_t)(b * 16 + h) * 1024 + n) * 64;
          dst[base + d1]      = f2bf(o1);
          dst[base + d1 + 32] = f2bf(o2);
        }
    }
  } else {
    // V^T [bh][d=64][n=1024]; acc reg axis r = consecutive n -> 8B packed stores
    #pragma unroll
    for (int nt = 0; nt < 4; ++nt) {
      int col = tcol + wc * 64 + nt * 16 + l15;
      int hc = col & 1023, h = hc >> 6, d = hc & 63;
      #pragma unroll
      for (int mi = 0; mi < 4; ++mi) {
        int rowg = trow + wr * 64 + mi * 16 + g * 4;
        int b = rowg >> 10, n0 = rowg & 1023;
        ushort4 pk;
        pk.x = (unsigned short)f2bf(acc[mi][nt][0]);
        pk.y = (unsigned short)f2bf(acc[mi][nt][1]);
        pk.z = (unsigned short)f2bf(acc[mi][nt][2]);
        pk.w = (unsigned short)f2bf(acc[mi][nt][3]);
        *reinterpret_cast<ushort4*>((unsigned short*)vt +
            ((size_t)(b * 16 + h) * 64 + d) * 1024 + n0) = pk;
      }
    }
  }
}

// Proj GEMM: attn_out bf16 [8192x1024] x proj_w bf16 [1024x1024]^T + bias -> fp32
__global__ __launch_bounds__(256) void gemm_proj_k(const short* __restrict__ A,
                                                   const short* __restrict__ Bm,
                                                   const float* __restrict__ pb,
                                                   float* __restrict__ out) {
  __shared__ __align__(16) short As[128 * 64];
  __shared__ __align__(16) short Bs[128 * 64];
  // XCD-aware bijective swizzle: nwg = 8*64 = 512, 512 % 8 == 0.
  const int id  = blockIdx.y * 8 + blockIdx.x;
  const int sid = (id & 7) * 64 + (id >> 3);
  const int bx  = sid % 8, by = sid / 8;
  floatx4 acc[4][4];
  gemm_main(A, Bm, As, Bs, acc, bx, by);

  const int tid = threadIdx.x;
  const int wid = tid >> 6, lane = tid & 63;
  const int g = lane >> 4, l15 = lane & 15;
  const int wr = wid >> 1, wc = wid & 1;
  const int trow = by * 128, tcol = bx * 128;
  #pragma unroll
  for (int nt = 0; nt < 4; ++nt) {
    int col = tcol + wc * 64 + nt * 16 + l15;
    float bias = pb[col];
    #pragma unroll
    for (int mi = 0; mi < 4; ++mi)
      #pragma unroll
      for (int r = 0; r < 4; ++r) {
        int rowg = trow + wr * 64 + mi * 16 + g * 4 + r;
        out[(size_t)rowg * 1024 + col] = acc[mi][nt][r] + bias;
      }
  }
}

// ---------------- flash attention (swapped-QK^T, register softmax) ----------------
// VERBATIM the round-3-passing version (90.7us, absmax 3.66e-4).
// grid (16 q-tiles, 128 bh); 4 waves x 16 q-rows.  KV tile 64, double-buffered.
// S^T = mfma(K,Q): lane (g,l15) owns q=l15, k = kt*16+4g+r -> per-lane scalar m,l.
// P redistribution: 4x permlane32_swap + 4x permlane16_swap.
__global__ __launch_bounds__(256) void attn_kernel(const short* __restrict__ qs,
                                                   const short* __restrict__ ksrc,
                                                   const short* __restrict__ vt,
                                                   short* __restrict__ aout) {
  __shared__ __align__(16) short Kl[2][64 * 64];
  __shared__ __align__(16) short Vl[2][64 * 64];

  const int tid = threadIdx.x, wid = tid >> 6, lane = tid & 63;
  const int g = lane >> 4, l15 = lane & 15;
  const int bh = blockIdx.y, q0 = blockIdx.x * 64;
  const size_t bhoff = (size_t)bh * 1024 * 64;
  const short* Kb = ksrc + bhoff;          // [n][d]
  const short* Vb = vt + bhoff;            // [d][n]

  const short* Qp = qs + bhoff + (size_t)(q0 + wid * 16 + l15) * 64 + g * 8;
  bf16x8 qf0 = *reinterpret_cast<const bf16x8*>(Qp);
  bf16x8 qf1 = *reinterpret_cast<const bf16x8*>(Qp + 32);

  floatx4 o[4];
  floatx4 zero = {0.f, 0.f, 0.f, 0.f};
  #pragma unroll
  for (int i = 0; i < 4; ++i) o[i] = zero;
  float mrun = -1e30f, lrun = 0.f;

  auto stage = [&](int buf, int t) {
    #pragma unroll
    for (int i = 0; i < 2; ++i) {
      const int cb = (i * 4 + wid) * 64;         // wave-uniform chunk base
      const int c = cb + lane;
      const int r = c >> 3, s = c & 7;
      const int off = (s ^ (r & 7)) << 3;        // pre-swizzled source
      gld16(Kb + (size_t)(t * 64 + r) * 64 + off, &Kl[buf][cb * 8]);
      gld16(Vb + (size_t)r * 1024 + t * 64 + off, &Vl[buf][cb * 8]);
    }
  };

  stage(0, 0);
  __syncthreads();

  for (int t = 0; t < 16; ++t) {
    const int buf = t & 1;
    if (t < 15) stage(buf ^ 1, t + 1);           // loads fly under compute

    // ---- S^T = K Q^T : D[k][q], 8 MFMA ----
    floatx4 s4[4];
    #pragma unroll
    for (int kt = 0; kt < 4; ++kt) s4[kt] = zero;
    __builtin_amdgcn_s_setprio(1);
    #pragma unroll
    for (int kt = 0; kt < 4; ++kt) {
      int krow = kt * 16 + l15;
      int ch0 = (g ^ (krow & 7)) << 3, ch1 = (((4 + g)) ^ (krow & 7)) << 3;
      bf16x8 kf0 = *reinterpret_cast<const bf16x8*>(&Kl[buf][krow * 64 + ch0]);
      s4[kt] = __builtin_amdgcn_mfma_f32_16x16x32_bf16(kf0, qf0, s4[kt], 0, 0, 0);
      bf16x8 kf1 = *reinterpret_cast<const bf16x8*>(&Kl[buf][krow * 64 + ch1]);
      s4[kt] = __builtin_amdgcn_mfma_f32_16x16x32_bf16(kf1, qf1, s4[kt], 0, 0, 0);
    }
    __builtin_amdgcn_s_setprio(0);

    // ---- per-lane online softmax (q = l15), defer-max (THR=8 in exp2 dom) ----
    float m0 = -1e30f;
    #pragma unroll
    for (int kt = 0; kt < 4; ++kt)
      m0 = fmaxf(m0, fmaxf(fmaxf(s4[kt][0], s4[kt][1]), fmaxf(s4[kt][2], s4[kt][3])));
    m0 = fmaxf(m0, __shfl_xor(m0, 16));
    m0 = fmaxf(m0, __shfl_xor(m0, 32));

    if (!__all(m0 - mrun <= 8.f)) {
      float mnew = fmaxf(mrun, m0);
      float alpha = exp2f(mrun - mnew);
      mrun = mnew;
      lrun *= alpha;
      const int slb = (lane & 48) + ((lane >> 4) << 2);
      float a4[4];
      #pragma unroll
      for (int r = 0; r < 4; ++r) a4[r] = __shfl(alpha, slb + r);
      #pragma unroll
      for (int nt = 0; nt < 4; ++nt) {
        o[nt][0] *= a4[0]; o[nt][1] *= a4[1]; o[nt][2] *= a4[2]; o[nt][3] *= a4[3];
      }
    }

    float p[4][4], lsum = 0.f;
    #pragma unroll
    for (int kt = 0; kt < 4; ++kt)
      #pragma unroll
      for (int r = 0; r < 4; ++r) {
        p[kt][r] = exp2f(s4[kt][r] - mrun);
        lsum += p[kt][r];
      }
    lsum += __shfl_xor(lsum, 16);
    lsum += __shfl_xor(lsum, 32);
    lrun += lsum;

    // ---- pack P to bf16 pairs: w[kt][h] covers k = kt*16+4g+2h+{0,1} ----
    unsigned w[4][2];
    #pragma unroll
    for (int kt = 0; kt < 4; ++kt) {
      w[kt][0] = cvtpk(p[kt][0], p[kt][1]);
      w[kt][1] = cvtpk(p[kt][2], p[kt][3]);
    }

    // ---- butterfly via permlane swaps: dest W[ks][b][h] ----
    unsigned W[2][2][2];
    #pragma unroll
    for (int ks = 0; ks < 2; ++ks)
      #pragma unroll
      for (int h = 0; h < 2; ++h) {
        u32x2 y = __builtin_amdgcn_permlane32_swap(w[2 * ks][h], w[2 * ks + 1][h],
                                                   false, false);
        u32x2 z = __builtin_amdgcn_permlane16_swap(y[0], y[1], false, false);
        W[ks][0][h] = z[0];
        W[ks][1][h] = z[1];
      }
    u32x4 aw0 = {W[0][0][0], W[0][0][1], W[0][1][0], W[0][1][1]};
    u32x4 aw1 = {W[1][0][0], W[1][0][1], W[1][1][0], W[1][1][1]};
    bf16x8 pa0 = __builtin_bit_cast(bf16x8, aw0);
    bf16x8 pa1 = __builtin_bit_cast(bf16x8, aw1);

    // ---- O += P V : B = V^T rows (d), 8 MFMA ----
    __builtin_amdgcn_s_setprio(1);
    #pragma unroll
    for (int nt = 0; nt < 4; ++nt) {
      int row = nt * 16 + l15;
      int ch0 = (g ^ (row & 7)) << 3, ch1 = ((4 + g) ^ (row & 7)) << 3;
      bf16x8 vf0 = *reinterpret_cast<const bf16x8*>(&Vl[buf][row * 64 + ch0]);
      o[nt] = __builtin_amdgcn_mfma_f32_16x16x32_bf16(pa0, vf0, o[nt], 0, 0, 0);
      bf16x8 vf1 = *reinterpret_cast<const bf16x8*>(&Vl[buf][row * 64 + ch1]);
      o[nt] = __builtin_amdgcn_mfma_f32_16x16x32_bf16(pa1, vf1, o[nt], 0, 0, 0);
    }
    __builtin_amdgcn_s_setprio(0);
    __syncthreads();   // staged t+1 complete (barrier drains vmcnt); buf reusable
  }

  // ---- epilogue: O/l -> attn_out bf16 [B][N][C];  row q = 4g+r, col d = nt*16+l15
  const int b = bh >> 4, h = bh & 15;
  const int slb = (lane & 48) + ((lane >> 4) << 2);
  float inv = 1.f / lrun;
  #pragma unroll
  for (int r = 0; r < 4; ++r) {
    float ir = __shfl(inv, slb + r);
    int n = q0 + wid * 16 + g * 4 + r;
    size_t base = ((size_t)(b * 1024) + n) * 1024 + h * 64;
    #pragma unroll
    for (int nt = 0; nt < 4; ++nt)
      aout[base + nt * 16 + l15] = f2bf(o[nt][r] * ir);
  }
}

// ---------------------------------------------------------------------------
extern "C" void kernel_launch(void* const* d_in, const int* in_sizes, int n_in,
                              void* d_out, int out_size, void* d_ws, size_t ws_size,
                              hipStream_t stream) {
  const float* x      = (const float*)d_in[0];   // [8,1024,1024]
  const float* ropef  = (const float*)d_in[1];   // [1,1024,1,64]
  const float* qkv_w  = (const float*)d_in[2];   // [3072,1024]
  const float* proj_w = (const float*)d_in[3];   // [1024,1024]
  const float* proj_b = (const float*)d_in[4];   // [1024]
  float* out = (float*)d_out;

  char* ws = (char*)d_ws;
  short*  xb  = (short*)(ws + 0);            // 16 MB  x bf16        (contiguous with)
  short*  wqb = (short*)(ws + 16777216);     //  6 MB  qkv_w bf16    (contiguous with)
  short*  wpb = (short*)(ws + 23068672);     //  2 MB  proj_w bf16
  short*  qb  = (short*)(ws + 25165824);     // 16 MB  q [bh][n][d] (RoPE+scale)
  short*  kb  = (short*)(ws + 41943040);     // 16 MB  k [bh][n][d] (RoPE)
  short*  vtb = (short*)(ws + 58720256);     // 16 MB  v^T [bh][d][n]
  short*  aob = (short*)(ws + 75497472);     // 16 MB  attn out bf16 [B][N][C]
  float2* tbl = (float2*)(ws + 92274688);    // 512 KB cos/sin table

  cvt_bf16_all<<<12288, 256, 0, stream>>>(x, qkv_w, proj_w, xb);
  rope_table<<<256, 256, 0, stream>>>(ropef, tbl);

  gemm_qkv_k<<<dim3(24, 64), 256, 0, stream>>>(xb, wqb, tbl, qb, kb, vtb);
  attn_kernel<<<dim3(16, 128), 256, 0, stream>>>(qb, kb, vtb, aob);
  gemm_proj_k<<<dim3(8, 64), 256, 0, stream>>>(aob, wpb, proj_b, out);
}

// Round 7
// 188.869 us; speedup vs baseline: 1.4558x; 1.0282x over previous
//
#include <hip/hip_runtime.h>

// ---------------------------------------------------------------------------
// Fused attention block: qkv-proj(+RoPE fused) -> flash attention -> out-proj
// B=8 N=1024 C=1024 H=16 D=64.  All matmuls bf16 MFMA 16x16x32, fp32 acc.
// ---------------------------------------------------------------------------

typedef __attribute__((ext_vector_type(8))) short bf16x8;
typedef __attribute__((ext_vector_type(4))) float floatx4;
typedef __attribute__((ext_vector_type(4))) unsigned int u32x4;
typedef __attribute__((ext_vector_type(2))) unsigned int u32x2;

__device__ __forceinline__ void gld16(const void* g, void* l) {
  __builtin_amdgcn_global_load_lds((const __attribute__((address_space(1))) void*)g,
                                   (__attribute__((address_space(3))) void*)l, 16, 0, 0);
}

__device__ __forceinline__ short f2bf(float f) {          // RNE fp32->bf16
  unsigned u = __builtin_bit_cast(unsigned, f);
  u = (u + 0x7FFFu + ((u >> 16) & 1u)) >> 16;
  return (short)u;
}
__device__ __forceinline__ unsigned cvtpk(float lo, float hi) {
  unsigned r;
  asm("v_cvt_pk_bf16_f32 %0, %1, %2" : "=v"(r) : "v"(lo), "v"(hi));
  return r;
}

// ---------------- prep: fp32->bf16 (x|qkv_w|proj_w) + RoPE cos/sin table ----------------
__global__ __launch_bounds__(256) void prep_all(const float* __restrict__ sx,
                                                const float* __restrict__ sq,
                                                const float* __restrict__ sp,
                                                short* __restrict__ dst,
                                                const float* __restrict__ ropef,
                                                float2* __restrict__ tbl) {
  int bid = blockIdx.x;
  if (bid < 12288) {
    int i = bid * 256 + threadIdx.x;          // 0 .. 3145728-1
    const float4* src;
    if (i < 2097152)      src = reinterpret_cast<const float4*>(sx) + i;
    else if (i < 2883584) src = reinterpret_cast<const float4*>(sq) + (i - 2097152);
    else                  src = reinterpret_cast<const float4*>(sp) + (i - 2883584);
    float4 v = *src;
    short4 o;
    o.x = f2bf(v.x); o.y = f2bf(v.y); o.z = f2bf(v.z); o.w = f2bf(v.w);
    reinterpret_cast<short4*>(dst)[i] = o;
  } else {
    int i = (bid - 12288) * 256 + threadIdx.x;   // 0 .. 65535
    float v = ropef[i];
    tbl[i] = make_float2(cosf(v), sinf(v));
  }
}

// scale (D^-0.5 = 1/8) * log2(e): softmax computed with exp2
#define QSCALE 0.18033688011112042f

// ---------------- GEMM core: C[128x128] = A[128xK] * B[128xK]^T, K=1024 ----------------
__device__ __forceinline__ void gemm_main(const short* __restrict__ A,
                                          const short* __restrict__ Bm,
                                          short* As, short* Bs,
                                          floatx4 (&acc)[4][4],
                                          int bx, int by) {
  const int tid = threadIdx.x;
  const int wid = tid >> 6, lane = tid & 63;
  const int g = lane >> 4, l15 = lane & 15;
  const int wr = wid >> 1, wc = wid & 1;
  const size_t trow = (size_t)by * 128, tcol = (size_t)bx * 128;
  floatx4 zero = {0.f, 0.f, 0.f, 0.f};
  #pragma unroll
  for (int i = 0; i < 4; ++i)
    #pragma unroll
    for (int j = 0; j < 4; ++j) acc[i][j] = zero;

  for (int k0 = 0; k0 < 1024; k0 += 64) {
    #pragma unroll
    for (int i = 0; i < 4; ++i) {
      const int cb = (i * 4 + wid) * 64;
      const int c  = cb + lane;
      const int r  = c >> 3, s = c & 7;
      const int koff = k0 + ((s ^ (r & 7)) << 3);
      gld16(A  + (trow + r) * 1024 + koff, As + (size_t)cb * 8);
      gld16(Bm + (tcol + r) * 1024 + koff, Bs + (size_t)cb * 8);
    }
    __syncthreads();
    #pragma unroll
    for (int ks = 0; ks < 2; ++ks) {
      bf16x8 af[4], bfr[4];
      #pragma unroll
      for (int mi = 0; mi < 4; ++mi) {
        int row = wr * 64 + mi * 16 + l15;
        int ch  = (ks * 4 + g) ^ (row & 7);
        af[mi] = *reinterpret_cast<const bf16x8*>(As + row * 64 + ch * 8);
      }
      #pragma unroll
      for (int nt = 0; nt < 4; ++nt) {
        int row = wc * 64 + nt * 16 + l15;
        int ch  = (ks * 4 + g) ^ (row & 7);
        bfr[nt] = *reinterpret_cast<const bf16x8*>(Bs + row * 64 + ch * 8);
      }
      #pragma unroll
      for (int mi = 0; mi < 4; ++mi)
        #pragma unroll
        for (int nt = 0; nt < 4; ++nt)
          acc[mi][nt] = __builtin_amdgcn_mfma_f32_16x16x32_bf16(af[mi], bfr[nt],
                                                                acc[mi][nt], 0, 0, 0);
    }
    __syncthreads();
  }
}

// QKV GEMM with fused RoPE epilogue.  bx: 0..7 -> q, 8..15 -> k, 16..23 -> v.
// q/k written [bh][n][d] with RoPE (q also pre-scaled); v written TRANSPOSED [bh][d][n].
__global__ __launch_bounds__(256) void gemm_qkv_k(const short* __restrict__ A,
                                                  const short* __restrict__ Bm,
                                                  const float2* __restrict__ tbl,
                                                  short* __restrict__ qo,
                                                  short* __restrict__ ko,
                                                  short* __restrict__ vt) {
  __shared__ __align__(16) short As[128 * 64];
  __shared__ __align__(16) short Bs[128 * 64];
  // XCD-aware bijective swizzle: nwg = 24*64 = 1536, 1536 % 8 == 0.
  const int id  = blockIdx.y * 24 + blockIdx.x;
  const int sid = (id & 7) * 192 + (id >> 3);
  const int bx  = sid % 24, by = sid / 24;
  floatx4 acc[4][4];
  gemm_main(A, Bm, As, Bs, acc, bx, by);

  const int tid = threadIdx.x;
  const int wid = tid >> 6, lane = tid & 63;
  const int g = lane >> 4, l15 = lane & 15;
  const int wr = wid >> 1, wc = wid & 1;
  const int trow = by * 128, tcol = bx * 128;
  const int which = bx >> 3;

  if (which < 2) {
    short* dst = which == 0 ? qo : ko;
    const float sc = which == 0 ? QSCALE : 1.0f;
    #pragma unroll
    for (int nt = 0; nt < 2; ++nt) {              // pairs (nt, nt+2) = (d, d+32)
      int col = tcol + wc * 64 + nt * 16 + l15;
      int hc = col & 1023, h = hc >> 6, d1 = hc & 63;   // d1 in [0,32)
      #pragma unroll
      for (int mi = 0; mi < 4; ++mi)
        #pragma unroll
        for (int r = 0; r < 4; ++r) {
          int rowg = trow + wr * 64 + mi * 16 + g * 4 + r;
          int b = rowg >> 10, n = rowg & 1023;
          float a1 = acc[mi][nt][r], a2 = acc[mi][nt + 2][r];
          float2 c1 = tbl[n * 64 + d1];
          float2 c2 = tbl[n * 64 + d1 + 32];
          float o1 = (a1 * c1.x - a2 * c1.y) * sc;
          float o2 = (a2 * c2.x + a1 * c2.y) * sc;
          size_t base = ((size_t)(b * 16 + h) * 1024 + n) * 64;
          dst[base + d1]      = f2bf(o1);
          dst[base + d1 + 32] = f2bf(o2);
        }
    }
  } else {
    // V^T [bh][d=64][n=1024]; acc reg axis r = consecutive n -> 8B packed stores
    #pragma unroll
    for (int nt = 0; nt < 4; ++nt) {
      int col = tcol + wc * 64 + nt * 16 + l15;
      int hc = col & 1023, h = hc >> 6, d = hc & 63;
      #pragma unroll
      for (int mi = 0; mi < 4; ++mi) {
        int rowg = trow + wr * 64 + mi * 16 + g * 4;
        int b = rowg >> 10, n0 = rowg & 1023;
        ushort4 pk;
        pk.x = (unsigned short)f2bf(acc[mi][nt][0]);
        pk.y = (unsigned short)f2bf(acc[mi][nt][1]);
        pk.z = (unsigned short)f2bf(acc[mi][nt][2]);
        pk.w = (unsigned short)f2bf(acc[mi][nt][3]);
        *reinterpret_cast<ushort4*>((unsigned short*)vt +
            ((size_t)(b * 16 + h) * 64 + d) * 1024 + n0) = pk;
      }
    }
  }
}

// Proj GEMM: attn_out bf16 [8192x1024] x proj_w bf16 [1024x1024]^T + bias -> fp32
__global__ __launch_bounds__(256) void gemm_proj_k(const short* __restrict__ A,
                                                   const short* __restrict__ Bm,
                                                   const float* __restrict__ pb,
                                                   float* __restrict__ out) {
  __shared__ __align__(16) short As[128 * 64];
  __shared__ __align__(16) short Bs[128 * 64];
  // XCD-aware bijective swizzle: nwg = 8*64 = 512, 512 % 8 == 0.
  const int id  = blockIdx.y * 8 + blockIdx.x;
  const int sid = (id & 7) * 64 + (id >> 3);
  const int bx  = sid % 8, by = sid / 8;
  floatx4 acc[4][4];
  gemm_main(A, Bm, As, Bs, acc, bx, by);

  const int tid = threadIdx.x;
  const int wid = tid >> 6, lane = tid & 63;
  const int g = lane >> 4, l15 = lane & 15;
  const int wr = wid >> 1, wc = wid & 1;
  const int trow = by * 128, tcol = bx * 128;
  #pragma unroll
  for (int nt = 0; nt < 4; ++nt) {
    int col = tcol + wc * 64 + nt * 16 + l15;
    float bias = pb[col];
    #pragma unroll
    for (int mi = 0; mi < 4; ++mi)
      #pragma unroll
      for (int r = 0; r < 4; ++r) {
        int rowg = trow + wr * 64 + mi * 16 + g * 4 + r;
        out[(size_t)rowg * 1024 + col] = acc[mi][nt][r] + bias;
      }
  }
}

// ---------------- flash attention (swapped-QK^T, register softmax, 128-q blocks) ------
// grid (128 bh FASTEST, 8 q-tiles of 128): the 8 blocks sharing a bh land on one XCD
// (dispatch id = bh + 128*qt, 128%8==0) -> K/V stay L2-resident per XCD.
// Per block: TWO 64-q halves share each K/V tile; kf/vf ds_reads are reused for both
// halves' MFMAs (32 MFMA per barrier period; staging/barrier costs halved per work).
// Sync skeleton is verbatim the round-3-passing one (stage t+1, compute t, syncthreads).
__global__ __launch_bounds__(256) void attn_kernel(const short* __restrict__ qs,
                                                   const short* __restrict__ ksrc,
                                                   const short* __restrict__ vt,
                                                   short* __restrict__ aout) {
  __shared__ __align__(16) short Kl[2][64 * 64];
  __shared__ __align__(16) short Vl[2][64 * 64];

  const int tid = threadIdx.x, wid = tid >> 6, lane = tid & 63;
  const int g = lane >> 4, l15 = lane & 15;
  const int bh = blockIdx.x, q0 = blockIdx.y * 128;
  const size_t bhoff = (size_t)bh * 1024 * 64;
  const short* Kb = ksrc + bhoff;          // [n][d]
  const short* Vb = vt + bhoff;            // [d][n]
  const int slb = (lane & 48) + ((lane >> 4) << 2);

  // Q fragments for both halves: rows q0 + {0,64} + wid*16 + l15
  const short* QpA = qs + bhoff + (size_t)(q0 + wid * 16 + l15) * 64 + g * 8;
  bf16x8 qA0 = *reinterpret_cast<const bf16x8*>(QpA);
  bf16x8 qA1 = *reinterpret_cast<const bf16x8*>(QpA + 32);
  const short* QpB = QpA + 64 * 64;
  bf16x8 qB0 = *reinterpret_cast<const bf16x8*>(QpB);
  bf16x8 qB1 = *reinterpret_cast<const bf16x8*>(QpB + 32);

  floatx4 oA[4], oB[4];
  floatx4 zero = {0.f, 0.f, 0.f, 0.f};
  #pragma unroll
  for (int i = 0; i < 4; ++i) { oA[i] = zero; oB[i] = zero; }
  float mrunA = -1e30f, lrunA = 0.f;     // lrun is a PER-LANE partial (alpha is
  float mrunB = -1e30f, lrunB = 0.f;     // uniform across the 4 lanes of a q-row)

  auto stage = [&](int buf, int t) {
    #pragma unroll
    for (int i = 0; i < 2; ++i) {
      const int cb = (i * 4 + wid) * 64;         // wave-uniform chunk base
      const int c = cb + lane;
      const int r = c >> 3, s = c & 7;
      const int off = (s ^ (r & 7)) << 3;        // pre-swizzled source
      gld16(Kb + (size_t)(t * 64 + r) * 64 + off, &Kl[buf][cb * 8]);
      gld16(Vb + (size_t)r * 1024 + t * 64 + off, &Vl[buf][cb * 8]);
    }
  };

  // softmax for one half: s4 -> pa0/pa1 fragments, updates mrun/lrun/o.
#define SOFTMAX(s4, mrun, lrun, o, pa0, pa1)                                   \
  do {                                                                         \
    float m0 = -1e30f;                                                         \
    _Pragma("unroll")                                                          \
    for (int kt = 0; kt < 4; ++kt)                                             \
      m0 = fmaxf(m0, fmaxf(fmaxf(s4[kt][0], s4[kt][1]),                        \
                           fmaxf(s4[kt][2], s4[kt][3])));                      \
    m0 = fmaxf(m0, __shfl_xor(m0, 16));                                        \
    m0 = fmaxf(m0, __shfl_xor(m0, 32));                                        \
    if (!__all(m0 - mrun <= 8.f)) {                                            \
      float mnew = fmaxf(mrun, m0);                                            \
      float alpha = exp2f(mrun - mnew);                                        \
      mrun = mnew;                                                             \
      lrun *= alpha;                                                           \
      float a4[4];                                                             \
      _Pragma("unroll")                                                        \
      for (int r = 0; r < 4; ++r) a4[r] = __shfl(alpha, slb + r);              \
      _Pragma("unroll")                                                        \
      for (int nt = 0; nt < 4; ++nt) {                                         \
        o[nt][0] *= a4[0]; o[nt][1] *= a4[1];                                  \
        o[nt][2] *= a4[2]; o[nt][3] *= a4[3];                                  \
      }                                                                        \
    }                                                                          \
    unsigned w[4][2];                                                          \
    _Pragma("unroll")                                                          \
    for (int kt = 0; kt < 4; ++kt) {                                           \
      float p0 = exp2f(s4[kt][0] - mrun), p1 = exp2f(s4[kt][1] - mrun);        \
      float p2 = exp2f(s4[kt][2] - mrun), p3 = exp2f(s4[kt][3] - mrun);        \
      lrun += (p0 + p1) + (p2 + p3);                                           \
      w[kt][0] = cvtpk(p0, p1);                                                \
      w[kt][1] = cvtpk(p2, p3);                                                \
    }                                                                          \
    unsigned W[2][2][2];                                                       \
    _Pragma("unroll")                                                          \
    for (int ks = 0; ks < 2; ++ks)                                             \
      _Pragma("unroll")                                                        \
      for (int h = 0; h < 2; ++h) {                                            \
        u32x2 y = __builtin_amdgcn_permlane32_swap(w[2 * ks][h],               \
                                                   w[2 * ks + 1][h],           \
                                                   false, false);              \
        u32x2 z = __builtin_amdgcn_permlane16_swap(y[0], y[1], false, false);  \
        W[ks][0][h] = z[0];                                                    \
        W[ks][1][h] = z[1];                                                    \
      }                                                                        \
    u32x4 aw0 = {W[0][0][0], W[0][0][1], W[0][1][0], W[0][1][1]};              \
    u32x4 aw1 = {W[1][0][0], W[1][0][1], W[1][1][0], W[1][1][1]};              \
    pa0 = __builtin_bit_cast(bf16x8, aw0);                                     \
    pa1 = __builtin_bit_cast(bf16x8, aw1);                                     \
  } while (0)

  stage(0, 0);
  __syncthreads();

  for (int t = 0; t < 16; ++t) {
    const int buf = t & 1;
    if (t < 15) stage(buf ^ 1, t + 1);           // loads fly under compute

    // ---- S^T = K Q^T for BOTH halves off shared kf reads: 16 MFMA, 8 ds_read ----
    floatx4 sA[4], sB[4];
    #pragma unroll
    for (int kt = 0; kt < 4; ++kt) { sA[kt] = zero; sB[kt] = zero; }
    __builtin_amdgcn_s_setprio(1);
    #pragma unroll
    for (int kt = 0; kt < 4; ++kt) {
      int krow = kt * 16 + l15;
      int ch0 = (g ^ (krow & 7)) << 3, ch1 = ((4 + g) ^ (krow & 7)) << 3;
      bf16x8 kf0 = *reinterpret_cast<const bf16x8*>(&Kl[buf][krow * 64 + ch0]);
      sA[kt] = __builtin_amdgcn_mfma_f32_16x16x32_bf16(kf0, qA0, sA[kt], 0, 0, 0);
      sB[kt] = __builtin_amdgcn_mfma_f32_16x16x32_bf16(kf0, qB0, sB[kt], 0, 0, 0);
      bf16x8 kf1 = *reinterpret_cast<const bf16x8*>(&Kl[buf][krow * 64 + ch1]);
      sA[kt] = __builtin_amdgcn_mfma_f32_16x16x32_bf16(kf1, qA1, sA[kt], 0, 0, 0);
      sB[kt] = __builtin_amdgcn_mfma_f32_16x16x32_bf16(kf1, qB1, sB[kt], 0, 0, 0);
    }
    __builtin_amdgcn_s_setprio(0);

    // ---- softmax both halves ----
    bf16x8 paA0, paA1, paB0, paB1;
    SOFTMAX(sA, mrunA, lrunA, oA, paA0, paA1);
    SOFTMAX(sB, mrunB, lrunB, oB, paB0, paB1);

    // ---- O += P V for BOTH halves off shared vf reads: 16 MFMA, 8 ds_read ----
    __builtin_amdgcn_s_setprio(1);
    #pragma unroll
    for (int nt = 0; nt < 4; ++nt) {
      int row = nt * 16 + l15;
      int ch0 = (g ^ (row & 7)) << 3, ch1 = ((4 + g) ^ (row & 7)) << 3;
      bf16x8 vf0 = *reinterpret_cast<const bf16x8*>(&Vl[buf][row * 64 + ch0]);
      oA[nt] = __builtin_amdgcn_mfma_f32_16x16x32_bf16(paA0, vf0, oA[nt], 0, 0, 0);
      oB[nt] = __builtin_amdgcn_mfma_f32_16x16x32_bf16(paB0, vf0, oB[nt], 0, 0, 0);
      bf16x8 vf1 = *reinterpret_cast<const bf16x8*>(&Vl[buf][row * 64 + ch1]);
      oA[nt] = __builtin_amdgcn_mfma_f32_16x16x32_bf16(paA1, vf1, oA[nt], 0, 0, 0);
      oB[nt] = __builtin_amdgcn_mfma_f32_16x16x32_bf16(paB1, vf1, oB[nt], 0, 0, 0);
    }
    __builtin_amdgcn_s_setprio(0);
    __syncthreads();   // staged t+1 complete (barrier drains vmcnt); buf reusable
  }

  // ---- epilogue: finish lrun reduction (4 lanes per q-row), write both halves ----
  const int b = bh >> 4, h = bh & 15;
  lrunA += __shfl_xor(lrunA, 16); lrunA += __shfl_xor(lrunA, 32);
  lrunB += __shfl_xor(lrunB, 16); lrunB += __shfl_xor(lrunB, 32);
  float invA = 1.f / lrunA, invB = 1.f / lrunB;
  #pragma unroll
  for (int r = 0; r < 4; ++r) {
    float irA = __shfl(invA, slb + r);
    float irB = __shfl(invB, slb + r);
    int nA = q0 + wid * 16 + g * 4 + r;
    size_t baseA = ((size_t)(b * 1024) + nA) * 1024 + h * 64;
    size_t baseB = baseA + (size_t)64 * 1024;
    #pragma unroll
    for (int nt = 0; nt < 4; ++nt) {
      aout[baseA + nt * 16 + l15] = f2bf(oA[nt][r] * irA);
      aout[baseB + nt * 16 + l15] = f2bf(oB[nt][r] * irB);
    }
  }
#undef SOFTMAX
}

// ---------------------------------------------------------------------------
extern "C" void kernel_launch(void* const* d_in, const int* in_sizes, int n_in,
                              void* d_out, int out_size, void* d_ws, size_t ws_size,
                              hipStream_t stream) {
  const float* x      = (const float*)d_in[0];   // [8,1024,1024]
  const float* ropef  = (const float*)d_in[1];   // [1,1024,1,64]
  const float* qkv_w  = (const float*)d_in[2];   // [3072,1024]
  const float* proj_w = (const float*)d_in[3];   // [1024,1024]
  const float* proj_b = (const float*)d_in[4];   // [1024]
  float* out = (float*)d_out;

  char* ws = (char*)d_ws;
  short*  xb  = (short*)(ws + 0);            // 16 MB  x bf16        (contiguous with)
  short*  wqb = (short*)(ws + 16777216);     //  6 MB  qkv_w bf16    (contiguous with)
  short*  wpb = (short*)(ws + 23068672);     //  2 MB  proj_w bf16
  short*  qb  = (short*)(ws + 25165824);     // 16 MB  q [bh][n][d] (RoPE+scale)
  short*  kb  = (short*)(ws + 41943040);     // 16 MB  k [bh][n][d] (RoPE)
  short*  vtb = (short*)(ws + 58720256);     // 16 MB  v^T [bh][d][n]
  short*  aob = (short*)(ws + 75497472);     // 16 MB  attn out bf16 [B][N][C]
  float2* tbl = (float2*)(ws + 92274688);    // 512 KB cos/sin table

  prep_all<<<12544, 256, 0, stream>>>(x, qkv_w, proj_w, xb, ropef, tbl);

  gemm_qkv_k<<<dim3(24, 64), 256, 0, stream>>>(xb, wqb, tbl, qb, kb, vtb);
  attn_kernel<<<dim3(128, 8), 256, 0, stream>>>(qb, kb, vtb, aob);
  gemm_proj_k<<<dim3(8, 64), 256, 0, stream>>>(aob, wpb, proj_b, out);
}

// Round 8
// 171.719 us; speedup vs baseline: 1.6012x; 1.0999x over previous
//
#include <hip/hip_runtime.h>

// ---------------------------------------------------------------------------
// Fused attention block: qkv-proj(+RoPE fused) -> flash attention -> out-proj
// B=8 N=1024 C=1024 H=16 D=64.  All matmuls bf16 MFMA 16x16x32, fp32 acc.
// ---------------------------------------------------------------------------

typedef __attribute__((ext_vector_type(8))) short bf16x8;
typedef __attribute__((ext_vector_type(4))) float floatx4;
typedef __attribute__((ext_vector_type(4))) unsigned int u32x4;
typedef __attribute__((ext_vector_type(2))) unsigned int u32x2;

__device__ __forceinline__ void gld16(const void* g, void* l) {
  __builtin_amdgcn_global_load_lds((const __attribute__((address_space(1))) void*)g,
                                   (__attribute__((address_space(3))) void*)l, 16, 0, 0);
}

__device__ __forceinline__ short f2bf(float f) {          // RNE fp32->bf16
  unsigned u = __builtin_bit_cast(unsigned, f);
  u = (u + 0x7FFFu + ((u >> 16) & 1u)) >> 16;
  return (short)u;
}
__device__ __forceinline__ unsigned cvtpk(float lo, float hi) {
  unsigned r;
  asm("v_cvt_pk_bf16_f32 %0, %1, %2" : "=v"(r) : "v"(lo), "v"(hi));
  return r;
}
__device__ __forceinline__ float pexp(float x) {          // raw v_exp_f32 (2^x)
  float r;
  asm("v_exp_f32 %0, %1" : "=v"(r) : "v"(x));
  return r;
}
__device__ __forceinline__ float max3f(float a, float b, float c) {
  float r;
  asm("v_max3_f32 %0, %1, %2, %3" : "=v"(r) : "v"(a), "v"(b), "v"(c));
  return r;
}
// max over lanes {l, l^16, l^32, l^48} via permlane swaps (VALU-only).
// CRITICAL: the two operands of permlane*_swap must be DISTINCT registers
// (in-place two-reg exchange); force a copy via opaque v_mov.  (R4/R5 post-
// mortem: same-reg tie degenerates to a self-swap -> wrong max -> small
// deterministic softmax rounding error.)
__device__ __forceinline__ float pl_max(float x) {
  unsigned a = __builtin_bit_cast(unsigned, x), b;
  asm("v_mov_b32 %0, %1" : "=v"(b) : "v"(a));
  u32x2 y = __builtin_amdgcn_permlane32_swap(a, b, false, false);
  float m = fmaxf(__builtin_bit_cast(float, y[0]), __builtin_bit_cast(float, y[1]));
  unsigned c = __builtin_bit_cast(unsigned, m), d;
  asm("v_mov_b32 %0, %1" : "=v"(d) : "v"(c));
  u32x2 z = __builtin_amdgcn_permlane16_swap(c, d, false, false);
  return fmaxf(__builtin_bit_cast(float, z[0]), __builtin_bit_cast(float, z[1]));
}

// ---------------- prep: fp32->bf16 (x|qkv_w|proj_w) + RoPE cos/sin table ----------------
__global__ __launch_bounds__(256) void prep_all(const float* __restrict__ sx,
                                                const float* __restrict__ sq,
                                                const float* __restrict__ sp,
                                                short* __restrict__ dst,
                                                const float* __restrict__ ropef,
                                                float2* __restrict__ tbl) {
  int bid = blockIdx.x;
  if (bid < 12288) {
    int i = bid * 256 + threadIdx.x;          // 0 .. 3145728-1
    const float4* src;
    if (i < 2097152)      src = reinterpret_cast<const float4*>(sx) + i;
    else if (i < 2883584) src = reinterpret_cast<const float4*>(sq) + (i - 2097152);
    else                  src = reinterpret_cast<const float4*>(sp) + (i - 2883584);
    float4 v = *src;
    short4 o;
    o.x = f2bf(v.x); o.y = f2bf(v.y); o.z = f2bf(v.z); o.w = f2bf(v.w);
    reinterpret_cast<short4*>(dst)[i] = o;
  } else {
    int i = (bid - 12288) * 256 + threadIdx.x;   // 0 .. 65535
    float v = ropef[i];
    tbl[i] = make_float2(cosf(v), sinf(v));
  }
}

// scale (D^-0.5 = 1/8) * log2(e): softmax computed with exp2
#define QSCALE 0.18033688011112042f

// ---------------- GEMM core: C[128x128] = A[128xK] * B[128xK]^T, K=1024 ----------------
__device__ __forceinline__ void gemm_main(const short* __restrict__ A,
                                          const short* __restrict__ Bm,
                                          short* As, short* Bs,
                                          floatx4 (&acc)[4][4],
                                          int bx, int by) {
  const int tid = threadIdx.x;
  const int wid = tid >> 6, lane = tid & 63;
  const int g = lane >> 4, l15 = lane & 15;
  const int wr = wid >> 1, wc = wid & 1;
  const size_t trow = (size_t)by * 128, tcol = (size_t)bx * 128;
  floatx4 zero = {0.f, 0.f, 0.f, 0.f};
  #pragma unroll
  for (int i = 0; i < 4; ++i)
    #pragma unroll
    for (int j = 0; j < 4; ++j) acc[i][j] = zero;

  for (int k0 = 0; k0 < 1024; k0 += 64) {
    #pragma unroll
    for (int i = 0; i < 4; ++i) {
      const int cb = (i * 4 + wid) * 64;
      const int c  = cb + lane;
      const int r  = c >> 3, s = c & 7;
      const int koff = k0 + ((s ^ (r & 7)) << 3);
      gld16(A  + (trow + r) * 1024 + koff, As + (size_t)cb * 8);
      gld16(Bm + (tcol + r) * 1024 + koff, Bs + (size_t)cb * 8);
    }
    __syncthreads();
    #pragma unroll
    for (int ks = 0; ks < 2; ++ks) {
      bf16x8 af[4], bfr[4];
      #pragma unroll
      for (int mi = 0; mi < 4; ++mi) {
        int row = wr * 64 + mi * 16 + l15;
        int ch  = (ks * 4 + g) ^ (row & 7);
        af[mi] = *reinterpret_cast<const bf16x8*>(As + row * 64 + ch * 8);
      }
      #pragma unroll
      for (int nt = 0; nt < 4; ++nt) {
        int row = wc * 64 + nt * 16 + l15;
        int ch  = (ks * 4 + g) ^ (row & 7);
        bfr[nt] = *reinterpret_cast<const bf16x8*>(Bs + row * 64 + ch * 8);
      }
      #pragma unroll
      for (int mi = 0; mi < 4; ++mi)
        #pragma unroll
        for (int nt = 0; nt < 4; ++nt)
          acc[mi][nt] = __builtin_amdgcn_mfma_f32_16x16x32_bf16(af[mi], bfr[nt],
                                                                acc[mi][nt], 0, 0, 0);
    }
    __syncthreads();
  }
}

// QKV GEMM with fused RoPE epilogue.  bx: 0..7 -> q, 8..15 -> k, 16..23 -> v.
// q/k written [bh][n][d] with RoPE (q also pre-scaled); v written TRANSPOSED [bh][d][n].
__global__ __launch_bounds__(256) void gemm_qkv_k(const short* __restrict__ A,
                                                  const short* __restrict__ Bm,
                                                  const float2* __restrict__ tbl,
                                                  short* __restrict__ qo,
                                                  short* __restrict__ ko,
                                                  short* __restrict__ vt) {
  __shared__ __align__(16) short As[128 * 64];
  __shared__ __align__(16) short Bs[128 * 64];
  // XCD-aware bijective swizzle: nwg = 24*64 = 1536, 1536 % 8 == 0.
  const int id  = blockIdx.y * 24 + blockIdx.x;
  const int sid = (id & 7) * 192 + (id >> 3);
  const int bx  = sid % 24, by = sid / 24;
  floatx4 acc[4][4];
  gemm_main(A, Bm, As, Bs, acc, bx, by);

  const int tid = threadIdx.x;
  const int wid = tid >> 6, lane = tid & 63;
  const int g = lane >> 4, l15 = lane & 15;
  const int wr = wid >> 1, wc = wid & 1;
  const int trow = by * 128, tcol = bx * 128;
  const int which = bx >> 3;

  if (which < 2) {
    short* dst = which == 0 ? qo : ko;
    const float sc = which == 0 ? QSCALE : 1.0f;
    #pragma unroll
    for (int nt = 0; nt < 2; ++nt) {              // pairs (nt, nt+2) = (d, d+32)
      int col = tcol + wc * 64 + nt * 16 + l15;
      int hc = col & 1023, h = hc >> 6, d1 = hc & 63;   // d1 in [0,32)
      #pragma unroll
      for (int mi = 0; mi < 4; ++mi)
        #pragma unroll
        for (int r = 0; r < 4; ++r) {
          int rowg = trow + wr * 64 + mi * 16 + g * 4 + r;
          int b = rowg >> 10, n = rowg & 1023;
          float a1 = acc[mi][nt][r], a2 = acc[mi][nt + 2][r];
          float2 c1 = tbl[n * 64 + d1];
          float2 c2 = tbl[n * 64 + d1 + 32];
          float o1 = (a1 * c1.x - a2 * c1.y) * sc;
          float o2 = (a2 * c2.x + a1 * c2.y) * sc;
          size_t base = ((size_t)(b * 16 + h) * 1024 + n) * 64;
          dst[base + d1]      = f2bf(o1);
          dst[base + d1 + 32] = f2bf(o2);
        }
    }
  } else {
    // V^T [bh][d=64][n=1024]; acc reg axis r = consecutive n -> 8B packed stores
    #pragma unroll
    for (int nt = 0; nt < 4; ++nt) {
      int col = tcol + wc * 64 + nt * 16 + l15;
      int hc = col & 1023, h = hc >> 6, d = hc & 63;
      #pragma unroll
      for (int mi = 0; mi < 4; ++mi) {
        int rowg = trow + wr * 64 + mi * 16 + g * 4;
        int b = rowg >> 10, n0 = rowg & 1023;
        ushort4 pk;
        pk.x = (unsigned short)f2bf(acc[mi][nt][0]);
        pk.y = (unsigned short)f2bf(acc[mi][nt][1]);
        pk.z = (unsigned short)f2bf(acc[mi][nt][2]);
        pk.w = (unsigned short)f2bf(acc[mi][nt][3]);
        *reinterpret_cast<ushort4*>((unsigned short*)vt +
            ((size_t)(b * 16 + h) * 64 + d) * 1024 + n0) = pk;
      }
    }
  }
}

// Proj GEMM: attn_out bf16 [8192x1024] x proj_w bf16 [1024x1024]^T + bias -> fp32
__global__ __launch_bounds__(256) void gemm_proj_k(const short* __restrict__ A,
                                                   const short* __restrict__ Bm,
                                                   const float* __restrict__ pb,
                                                   float* __restrict__ out) {
  __shared__ __align__(16) short As[128 * 64];
  __shared__ __align__(16) short Bs[128 * 64];
  // XCD-aware bijective swizzle: nwg = 8*64 = 512, 512 % 8 == 0.
  const int id  = blockIdx.y * 8 + blockIdx.x;
  const int sid = (id & 7) * 64 + (id >> 3);
  const int bx  = sid % 8, by = sid / 8;
  floatx4 acc[4][4];
  gemm_main(A, Bm, As, Bs, acc, bx, by);

  const int tid = threadIdx.x;
  const int wid = tid >> 6, lane = tid & 63;
  const int g = lane >> 4, l15 = lane & 15;
  const int wr = wid >> 1, wc = wid & 1;
  const int trow = by * 128, tcol = bx * 128;
  #pragma unroll
  for (int nt = 0; nt < 4; ++nt) {
    int col = tcol + wc * 64 + nt * 16 + l15;
    float bias = pb[col];
    #pragma unroll
    for (int mi = 0; mi < 4; ++mi)
      #pragma unroll
      for (int r = 0; r < 4; ++r) {
        int rowg = trow + wr * 64 + mi * 16 + g * 4 + r;
        out[(size_t)rowg * 1024 + col] = acc[mi][nt][r] + bias;
      }
  }
}

// ---------------- flash attention (swapped-QK^T, register softmax, 128-q blocks) ------
// grid (128 bh FASTEST, 8 q-tiles of 128): 8 blocks sharing a bh land on one XCD.
// TWO 64-q halves share each K/V tile's ds_reads.  Sync skeleton = R3-passing one.
// R8: softmax internals only — asm v_exp_f32, v_max3_f32 tree, permlane max-reduce
// (forced-distinct-register copies).
__global__ __launch_bounds__(256) void attn_kernel(const short* __restrict__ qs,
                                                   const short* __restrict__ ksrc,
                                                   const short* __restrict__ vt,
                                                   short* __restrict__ aout) {
  __shared__ __align__(16) short Kl[2][64 * 64];
  __shared__ __align__(16) short Vl[2][64 * 64];

  const int tid = threadIdx.x, wid = tid >> 6, lane = tid & 63;
  const int g = lane >> 4, l15 = lane & 15;
  const int bh = blockIdx.x, q0 = blockIdx.y * 128;
  const size_t bhoff = (size_t)bh * 1024 * 64;
  const short* Kb = ksrc + bhoff;          // [n][d]
  const short* Vb = vt + bhoff;            // [d][n]
  const int slb = (lane & 48) + ((lane >> 4) << 2);

  // Q fragments for both halves: rows q0 + {0,64} + wid*16 + l15
  const short* QpA = qs + bhoff + (size_t)(q0 + wid * 16 + l15) * 64 + g * 8;
  bf16x8 qA0 = *reinterpret_cast<const bf16x8*>(QpA);
  bf16x8 qA1 = *reinterpret_cast<const bf16x8*>(QpA + 32);
  const short* QpB = QpA + 64 * 64;
  bf16x8 qB0 = *reinterpret_cast<const bf16x8*>(QpB);
  bf16x8 qB1 = *reinterpret_cast<const bf16x8*>(QpB + 32);

  floatx4 oA[4], oB[4];
  floatx4 zero = {0.f, 0.f, 0.f, 0.f};
  #pragma unroll
  for (int i = 0; i < 4; ++i) { oA[i] = zero; oB[i] = zero; }
  float mrunA = -1e30f, lrunA = 0.f;     // lrun is a PER-LANE partial (alpha is
  float mrunB = -1e30f, lrunB = 0.f;     // uniform across the 4 lanes of a q-row)

  auto stage = [&](int buf, int t) {
    #pragma unroll
    for (int i = 0; i < 2; ++i) {
      const int cb = (i * 4 + wid) * 64;         // wave-uniform chunk base
      const int c = cb + lane;
      const int r = c >> 3, s = c & 7;
      const int off = (s ^ (r & 7)) << 3;        // pre-swizzled source
      gld16(Kb + (size_t)(t * 64 + r) * 64 + off, &Kl[buf][cb * 8]);
      gld16(Vb + (size_t)r * 1024 + t * 64 + off, &Vl[buf][cb * 8]);
    }
  };

  // softmax for one half: s4 -> pa0/pa1 fragments, updates mrun/lrun/o.
#define SOFTMAX(s4, mrun, lrun, o, pa0, pa1)                                   \
  do {                                                                         \
    float t0 = max3f(s4[0][0], s4[0][1], s4[0][2]);                            \
    float t1 = max3f(s4[0][3], s4[1][0], s4[1][1]);                            \
    float t2 = max3f(s4[1][2], s4[1][3], s4[2][0]);                            \
    float t3 = max3f(s4[2][1], s4[2][2], s4[2][3]);                            \
    float t4 = max3f(s4[3][0], s4[3][1], s4[3][2]);                            \
    float u0 = max3f(t0, t1, t2);                                              \
    float u1 = max3f(t3, t4, s4[3][3]);                                        \
    float m0 = pl_max(fmaxf(u0, u1));                                          \
    if (!__all(m0 - mrun <= 8.f)) {                                            \
      float mnew = fmaxf(mrun, m0);                                            \
      float alpha = pexp(mrun - mnew);                                         \
      mrun = mnew;                                                             \
      lrun *= alpha;                                                           \
      float a4[4];                                                             \
      _Pragma("unroll")                                                        \
      for (int r = 0; r < 4; ++r) a4[r] = __shfl(alpha, slb + r);              \
      _Pragma("unroll")                                                        \
      for (int nt = 0; nt < 4; ++nt) {                                         \
        o[nt][0] *= a4[0]; o[nt][1] *= a4[1];                                  \
        o[nt][2] *= a4[2]; o[nt][3] *= a4[3];                                  \
      }                                                                        \
    }                                                                          \
    unsigned w[4][2];                                                          \
    _Pragma("unroll")                                                          \
    for (int kt = 0; kt < 4; ++kt) {                                           \
      float p0 = pexp(s4[kt][0] - mrun), p1 = pexp(s4[kt][1] - mrun);          \
      float p2 = pexp(s4[kt][2] - mrun), p3 = pexp(s4[kt][3] - mrun);          \
      lrun += (p0 + p1) + (p2 + p3);                                           \
      w[kt][0] = cvtpk(p0, p1);                                                \
      w[kt][1] = cvtpk(p2, p3);                                                \
    }                                                                          \
    unsigned W[2][2][2];                                                       \
    _Pragma("unroll")                                                          \
    for (int ks = 0; ks < 2; ++ks)                                             \
      _Pragma("unroll")                                                        \
      for (int h = 0; h < 2; ++h) {                                            \
        u32x2 y = __builtin_amdgcn_permlane32_swap(w[2 * ks][h],               \
                                                   w[2 * ks + 1][h],           \
                                                   false, false);              \
        u32x2 z = __builtin_amdgcn_permlane16_swap(y[0], y[1], false, false);  \
        W[ks][0][h] = z[0];                                                    \
        W[ks][1][h] = z[1];                                                    \
      }                                                                        \
    u32x4 aw0 = {W[0][0][0], W[0][0][1], W[0][1][0], W[0][1][1]};              \
    u32x4 aw1 = {W[1][0][0], W[1][0][1], W[1][1][0], W[1][1][1]};              \
    pa0 = __builtin_bit_cast(bf16x8, aw0);                                     \
    pa1 = __builtin_bit_cast(bf16x8, aw1);                                     \
  } while (0)

  stage(0, 0);
  __syncthreads();

  for (int t = 0; t < 16; ++t) {
    const int buf = t & 1;
    if (t < 15) stage(buf ^ 1, t + 1);           // loads fly under compute

    // ---- S^T = K Q^T for BOTH halves off shared kf reads: 16 MFMA, 8 ds_read ----
    floatx4 sA[4], sB[4];
    #pragma unroll
    for (int kt = 0; kt < 4; ++kt) { sA[kt] = zero; sB[kt] = zero; }
    __builtin_amdgcn_s_setprio(1);
    #pragma unroll
    for (int kt = 0; kt < 4; ++kt) {
      int krow = kt * 16 + l15;
      int ch0 = (g ^ (krow & 7)) << 3, ch1 = ((4 + g) ^ (krow & 7)) << 3;
      bf16x8 kf0 = *reinterpret_cast<const bf16x8*>(&Kl[buf][krow * 64 + ch0]);
      sA[kt] = __builtin_amdgcn_mfma_f32_16x16x32_bf16(kf0, qA0, sA[kt], 0, 0, 0);
      sB[kt] = __builtin_amdgcn_mfma_f32_16x16x32_bf16(kf0, qB0, sB[kt], 0, 0, 0);
      bf16x8 kf1 = *reinterpret_cast<const bf16x8*>(&Kl[buf][krow * 64 + ch1]);
      sA[kt] = __builtin_amdgcn_mfma_f32_16x16x32_bf16(kf1, qA1, sA[kt], 0, 0, 0);
      sB[kt] = __builtin_amdgcn_mfma_f32_16x16x32_bf16(kf1, qB1, sB[kt], 0, 0, 0);
    }
    __builtin_amdgcn_s_setprio(0);

    // ---- softmax both halves ----
    bf16x8 paA0, paA1, paB0, paB1;
    SOFTMAX(sA, mrunA, lrunA, oA, paA0, paA1);
    SOFTMAX(sB, mrunB, lrunB, oB, paB0, paB1);

    // ---- O += P V for BOTH halves off shared vf reads: 16 MFMA, 8 ds_read ----
    __builtin_amdgcn_s_setprio(1);
    #pragma unroll
    for (int nt = 0; nt < 4; ++nt) {
      int row = nt * 16 + l15;
      int ch0 = (g ^ (row & 7)) << 3, ch1 = ((4 + g) ^ (row & 7)) << 3;
      bf16x8 vf0 = *reinterpret_cast<const bf16x8*>(&Vl[buf][row * 64 + ch0]);
      oA[nt] = __builtin_amdgcn_mfma_f32_16x16x32_bf16(paA0, vf0, oA[nt], 0, 0, 0);
      oB[nt] = __builtin_amdgcn_mfma_f32_16x16x32_bf16(paB0, vf0, oB[nt], 0, 0, 0);
      bf16x8 vf1 = *reinterpret_cast<const bf16x8*>(&Vl[buf][row * 64 + ch1]);
      oA[nt] = __builtin_amdgcn_mfma_f32_16x16x32_bf16(paA1, vf1, oA[nt], 0, 0, 0);
      oB[nt] = __builtin_amdgcn_mfma_f32_16x16x32_bf16(paB1, vf1, oB[nt], 0, 0, 0);
    }
    __builtin_amdgcn_s_setprio(0);
    __syncthreads();   // staged t+1 complete (barrier drains vmcnt); buf reusable
  }

  // ---- epilogue: finish lrun reduction (4 lanes per q-row), write both halves ----
  const int b = bh >> 4, h = bh & 15;
  lrunA += __shfl_xor(lrunA, 16); lrunA += __shfl_xor(lrunA, 32);
  lrunB += __shfl_xor(lrunB, 16); lrunB += __shfl_xor(lrunB, 32);
  float invA = 1.f / lrunA, invB = 1.f / lrunB;
  #pragma unroll
  for (int r = 0; r < 4; ++r) {
    float irA = __shfl(invA, slb + r);
    float irB = __shfl(invB, slb + r);
    int nA = q0 + wid * 16 + g * 4 + r;
    size_t baseA = ((size_t)(b * 1024) + nA) * 1024 + h * 64;
    size_t baseB = baseA + (size_t)64 * 1024;
    #pragma unroll
    for (int nt = 0; nt < 4; ++nt) {
      aout[baseA + nt * 16 + l15] = f2bf(oA[nt][r] * irA);
      aout[baseB + nt * 16 + l15] = f2bf(oB[nt][r] * irB);
    }
  }
#undef SOFTMAX
}

// ---------------------------------------------------------------------------
extern "C" void kernel_launch(void* const* d_in, const int* in_sizes, int n_in,
                              void* d_out, int out_size, void* d_ws, size_t ws_size,
                              hipStream_t stream) {
  const float* x      = (const float*)d_in[0];   // [8,1024,1024]
  const float* ropef  = (const float*)d_in[1];   // [1,1024,1,64]
  const float* qkv_w  = (const float*)d_in[2];   // [3072,1024]
  const float* proj_w = (const float*)d_in[3];   // [1024,1024]
  const float* proj_b = (const float*)d_in[4];   // [1024]
  float* out = (float*)d_out;

  char* ws = (char*)d_ws;
  short*  xb  = (short*)(ws + 0);            // 16 MB  x bf16        (contiguous with)
  short*  wqb = (short*)(ws + 16777216);     //  6 MB  qkv_w bf16    (contiguous with)
  short*  wpb = (short*)(ws + 23068672);     //  2 MB  proj_w bf16
  short*  qb  = (short*)(ws + 25165824);     // 16 MB  q [bh][n][d] (RoPE+scale)
  short*  kb  = (short*)(ws + 41943040);     // 16 MB  k [bh][n][d] (RoPE)
  short*  vtb = (short*)(ws + 58720256);     // 16 MB  v^T [bh][d][n]
  short*  aob = (short*)(ws + 75497472);     // 16 MB  attn out bf16 [B][N][C]
  float2* tbl = (float2*)(ws + 92274688);    // 512 KB cos/sin table

  prep_all<<<12544, 256, 0, stream>>>(x, qkv_w, proj_w, xb, ropef, tbl);

  gemm_qkv_k<<<dim3(24, 64), 256, 0, stream>>>(xb, wqb, tbl, qb, kb, vtb);
  attn_kernel<<<dim3(128, 8), 256, 0, stream>>>(qb, kb, vtb, aob);
  gemm_proj_k<<<dim3(8, 64), 256, 0, stream>>>(aob, wpb, proj_b, out);
}

// Round 9
// 171.154 us; speedup vs baseline: 1.6065x; 1.0033x over previous
//
#include <hip/hip_runtime.h>

// ---------------------------------------------------------------------------
// Fused attention block: qkv-proj(+RoPE fused) -> flash attention -> out-proj
// B=8 N=1024 C=1024 H=16 D=64.  All matmuls bf16 MFMA 16x16x32, fp32 acc.
// ---------------------------------------------------------------------------

typedef __attribute__((ext_vector_type(8))) short bf16x8;
typedef __attribute__((ext_vector_type(4))) float floatx4;
typedef __attribute__((ext_vector_type(4))) unsigned int u32x4;
typedef __attribute__((ext_vector_type(2))) unsigned int u32x2;

__device__ __forceinline__ void gld16(const void* g, void* l) {
  __builtin_amdgcn_global_load_lds((const __attribute__((address_space(1))) void*)g,
                                   (__attribute__((address_space(3))) void*)l, 16, 0, 0);
}

__device__ __forceinline__ short f2bf(float f) {          // RNE fp32->bf16
  unsigned u = __builtin_bit_cast(unsigned, f);
  u = (u + 0x7FFFu + ((u >> 16) & 1u)) >> 16;
  return (short)u;
}
__device__ __forceinline__ unsigned cvtpk(float lo, float hi) {
  unsigned r;
  asm("v_cvt_pk_bf16_f32 %0, %1, %2" : "=v"(r) : "v"(lo), "v"(hi));
  return r;
}
__device__ __forceinline__ float pexp(float x) {          // raw v_exp_f32 (2^x)
  float r;
  asm("v_exp_f32 %0, %1" : "=v"(r) : "v"(x));
  return r;
}
__device__ __forceinline__ float max3f(float a, float b, float c) {
  float r;
  asm("v_max3_f32 %0, %1, %2, %3" : "=v"(r) : "v"(a), "v"(b), "v"(c));
  return r;
}
// max over lanes {l, l^16, l^32, l^48} via permlane swaps (VALU-only).
// Operands of permlane*_swap MUST be distinct registers (forced v_mov copy);
// same-reg tie degenerates to a self-swap (R4/R5 failure, confirmed by R8 pass).
__device__ __forceinline__ float pl_max(float x) {
  unsigned a = __builtin_bit_cast(unsigned, x), b;
  asm("v_mov_b32 %0, %1" : "=v"(b) : "v"(a));
  u32x2 y = __builtin_amdgcn_permlane32_swap(a, b, false, false);
  float m = fmaxf(__builtin_bit_cast(float, y[0]), __builtin_bit_cast(float, y[1]));
  unsigned c = __builtin_bit_cast(unsigned, m), d;
  asm("v_mov_b32 %0, %1" : "=v"(d) : "v"(c));
  u32x2 z = __builtin_amdgcn_permlane16_swap(c, d, false, false);
  return fmaxf(__builtin_bit_cast(float, z[0]), __builtin_bit_cast(float, z[1]));
}

// ---------------- prep: fp32->bf16 (x|qkv_w|proj_w) + RoPE cos/sin table ----------------
__global__ __launch_bounds__(256) void prep_all(const float* __restrict__ sx,
                                                const float* __restrict__ sq,
                                                const float* __restrict__ sp,
                                                short* __restrict__ dst,
                                                const float* __restrict__ ropef,
                                                float2* __restrict__ tbl) {
  int bid = blockIdx.x;
  if (bid < 12288) {
    int i = bid * 256 + threadIdx.x;          // 0 .. 3145728-1
    const float4* src;
    if (i < 2097152)      src = reinterpret_cast<const float4*>(sx) + i;
    else if (i < 2883584) src = reinterpret_cast<const float4*>(sq) + (i - 2097152);
    else                  src = reinterpret_cast<const float4*>(sp) + (i - 2883584);
    float4 v = *src;
    short4 o;
    o.x = f2bf(v.x); o.y = f2bf(v.y); o.z = f2bf(v.z); o.w = f2bf(v.w);
    reinterpret_cast<short4*>(dst)[i] = o;
  } else {
    int i = (bid - 12288) * 256 + threadIdx.x;   // 0 .. 65535
    float v = ropef[i];
    tbl[i] = make_float2(cosf(v), sinf(v));
  }
}

// scale (D^-0.5 = 1/8) * log2(e): softmax computed with exp2
#define QSCALE 0.18033688011112042f

// ---------------- GEMM core: C[128x128] = A[128xK] * B[128xK]^T, K=1024 ----------------
// DOUBLE-BUFFERED (R9): stage(k+1) issued BEFORE compute(k); one barrier per K-step
// (same proven skeleton as attn_kernel).  As/Bs are [2][128*64].
__device__ __forceinline__ void gemm_main(const short* __restrict__ A,
                                          const short* __restrict__ Bm,
                                          short* As, short* Bs,
                                          floatx4 (&acc)[4][4],
                                          int bx, int by) {
  const int tid = threadIdx.x;
  const int wid = tid >> 6, lane = tid & 63;
  const int g = lane >> 4, l15 = lane & 15;
  const int wr = wid >> 1, wc = wid & 1;
  const size_t trow = (size_t)by * 128, tcol = (size_t)bx * 128;
  floatx4 zero = {0.f, 0.f, 0.f, 0.f};
  #pragma unroll
  for (int i = 0; i < 4; ++i)
    #pragma unroll
    for (int j = 0; j < 4; ++j) acc[i][j] = zero;

  auto stage = [&](int buf, int k0) {
    #pragma unroll
    for (int i = 0; i < 4; ++i) {
      const int cb = (i * 4 + wid) * 64;      // wave-uniform chunk base
      const int c  = cb + lane;
      const int r  = c >> 3, s = c & 7;
      const int koff = k0 + ((s ^ (r & 7)) << 3);
      gld16(A  + (trow + r) * 1024 + koff, As + buf * 8192 + (size_t)cb * 8);
      gld16(Bm + (tcol + r) * 1024 + koff, Bs + buf * 8192 + (size_t)cb * 8);
    }
  };

  stage(0, 0);
  __syncthreads();

  for (int t = 0; t < 16; ++t) {
    const int buf = t & 1;
    if (t < 15) stage(buf ^ 1, (t + 1) * 64);     // loads fly under compute
    const short* Ab = As + buf * 8192;
    const short* Bb = Bs + buf * 8192;
    #pragma unroll
    for (int ks = 0; ks < 2; ++ks) {
      bf16x8 af[4], bfr[4];
      #pragma unroll
      for (int mi = 0; mi < 4; ++mi) {
        int row = wr * 64 + mi * 16 + l15;
        int ch  = (ks * 4 + g) ^ (row & 7);
        af[mi] = *reinterpret_cast<const bf16x8*>(Ab + row * 64 + ch * 8);
      }
      #pragma unroll
      for (int nt = 0; nt < 4; ++nt) {
        int row = wc * 64 + nt * 16 + l15;
        int ch  = (ks * 4 + g) ^ (row & 7);
        bfr[nt] = *reinterpret_cast<const bf16x8*>(Bb + row * 64 + ch * 8);
      }
      __builtin_amdgcn_s_setprio(1);
      #pragma unroll
      for (int mi = 0; mi < 4; ++mi)
        #pragma unroll
        for (int nt = 0; nt < 4; ++nt)
          acc[mi][nt] = __builtin_amdgcn_mfma_f32_16x16x32_bf16(af[mi], bfr[nt],
                                                                acc[mi][nt], 0, 0, 0);
      __builtin_amdgcn_s_setprio(0);
    }
    __syncthreads();   // staged t+1 complete (barrier drains vmcnt); buf reusable
  }
}

// QKV GEMM with fused RoPE epilogue.  bx: 0..7 -> q, 8..15 -> k, 16..23 -> v.
// q/k written [bh][n][d] with RoPE (q also pre-scaled); v written TRANSPOSED [bh][d][n].
__global__ __launch_bounds__(256) void gemm_qkv_k(const short* __restrict__ A,
                                                  const short* __restrict__ Bm,
                                                  const float2* __restrict__ tbl,
                                                  short* __restrict__ qo,
                                                  short* __restrict__ ko,
                                                  short* __restrict__ vt) {
  __shared__ __align__(16) short As[2 * 128 * 64];
  __shared__ __align__(16) short Bs[2 * 128 * 64];
  // XCD-aware bijective swizzle: nwg = 24*64 = 1536, 1536 % 8 == 0.
  const int id  = blockIdx.y * 24 + blockIdx.x;
  const int sid = (id & 7) * 192 + (id >> 3);
  const int bx  = sid % 24, by = sid / 24;
  floatx4 acc[4][4];
  gemm_main(A, Bm, As, Bs, acc, bx, by);

  const int tid = threadIdx.x;
  const int wid = tid >> 6, lane = tid & 63;
  const int g = lane >> 4, l15 = lane & 15;
  const int wr = wid >> 1, wc = wid & 1;
  const int trow = by * 128, tcol = bx * 128;
  const int which = bx >> 3;

  if (which < 2) {
    short* dst = which == 0 ? qo : ko;
    const float sc = which == 0 ? QSCALE : 1.0f;
    #pragma unroll
    for (int nt = 0; nt < 2; ++nt) {              // pairs (nt, nt+2) = (d, d+32)
      int col = tcol + wc * 64 + nt * 16 + l15;
      int hc = col & 1023, h = hc >> 6, d1 = hc & 63;   // d1 in [0,32)
      #pragma unroll
      for (int mi = 0; mi < 4; ++mi)
        #pragma unroll
        for (int r = 0; r < 4; ++r) {
          int rowg = trow + wr * 64 + mi * 16 + g * 4 + r;
          int b = rowg >> 10, n = rowg & 1023;
          float a1 = acc[mi][nt][r], a2 = acc[mi][nt + 2][r];
          float2 c1 = tbl[n * 64 + d1];
          float2 c2 = tbl[n * 64 + d1 + 32];
          float o1 = (a1 * c1.x - a2 * c1.y) * sc;
          float o2 = (a2 * c2.x + a1 * c2.y) * sc;
          size_t base = ((size_t)(b * 16 + h) * 1024 + n) * 64;
          dst[base + d1]      = f2bf(o1);
          dst[base + d1 + 32] = f2bf(o2);
        }
    }
  } else {
    // V^T [bh][d=64][n=1024]; acc reg axis r = consecutive n -> 8B packed stores
    #pragma unroll
    for (int nt = 0; nt < 4; ++nt) {
      int col = tcol + wc * 64 + nt * 16 + l15;
      int hc = col & 1023, h = hc >> 6, d = hc & 63;
      #pragma unroll
      for (int mi = 0; mi < 4; ++mi) {
        int rowg = trow + wr * 64 + mi * 16 + g * 4;
        int b = rowg >> 10, n0 = rowg & 1023;
        ushort4 pk;
        pk.x = (unsigned short)f2bf(acc[mi][nt][0]);
        pk.y = (unsigned short)f2bf(acc[mi][nt][1]);
        pk.z = (unsigned short)f2bf(acc[mi][nt][2]);
        pk.w = (unsigned short)f2bf(acc[mi][nt][3]);
        *reinterpret_cast<ushort4*>((unsigned short*)vt +
            ((size_t)(b * 16 + h) * 64 + d) * 1024 + n0) = pk;
      }
    }
  }
}

// Proj GEMM: attn_out bf16 [8192x1024] x proj_w bf16 [1024x1024]^T + bias -> fp32
__global__ __launch_bounds__(256) void gemm_proj_k(const short* __restrict__ A,
                                                   const short* __restrict__ Bm,
                                                   const float* __restrict__ pb,
                                                   float* __restrict__ out) {
  __shared__ __align__(16) short As[2 * 128 * 64];
  __shared__ __align__(16) short Bs[2 * 128 * 64];
  // XCD-aware bijective swizzle: nwg = 8*64 = 512, 512 % 8 == 0.
  const int id  = blockIdx.y * 8 + blockIdx.x;
  const int sid = (id & 7) * 64 + (id >> 3);
  const int bx  = sid % 8, by = sid / 8;
  floatx4 acc[4][4];
  gemm_main(A, Bm, As, Bs, acc, bx, by);

  const int tid = threadIdx.x;
  const int wid = tid >> 6, lane = tid & 63;
  const int g = lane >> 4, l15 = lane & 15;
  const int wr = wid >> 1, wc = wid & 1;
  const int trow = by * 128, tcol = bx * 128;
  #pragma unroll
  for (int nt = 0; nt < 4; ++nt) {
    int col = tcol + wc * 64 + nt * 16 + l15;
    float bias = pb[col];
    #pragma unroll
    for (int mi = 0; mi < 4; ++mi)
      #pragma unroll
      for (int r = 0; r < 4; ++r) {
        int rowg = trow + wr * 64 + mi * 16 + g * 4 + r;
        out[(size_t)rowg * 1024 + col] = acc[mi][nt][r] + bias;
      }
  }
}

// ---------------- flash attention (swapped-QK^T, register softmax, 128-q blocks) ------
// grid (128 bh FASTEST, 8 q-tiles of 128): 8 blocks sharing a bh land on one XCD.
// TWO 64-q halves share each K/V tile's ds_reads.  Sync skeleton = R3-passing one.
// asm v_exp_f32, v_max3_f32 tree, permlane max-reduce (forced-distinct registers).
__global__ __launch_bounds__(256) void attn_kernel(const short* __restrict__ qs,
                                                   const short* __restrict__ ksrc,
                                                   const short* __restrict__ vt,
                                                   short* __restrict__ aout) {
  __shared__ __align__(16) short Kl[2][64 * 64];
  __shared__ __align__(16) short Vl[2][64 * 64];

  const int tid = threadIdx.x, wid = tid >> 6, lane = tid & 63;
  const int g = lane >> 4, l15 = lane & 15;
  const int bh = blockIdx.x, q0 = blockIdx.y * 128;
  const size_t bhoff = (size_t)bh * 1024 * 64;
  const short* Kb = ksrc + bhoff;          // [n][d]
  const short* Vb = vt + bhoff;            // [d][n]
  const int slb = (lane & 48) + ((lane >> 4) << 2);

  // Q fragments for both halves: rows q0 + {0,64} + wid*16 + l15
  const short* QpA = qs + bhoff + (size_t)(q0 + wid * 16 + l15) * 64 + g * 8;
  bf16x8 qA0 = *reinterpret_cast<const bf16x8*>(QpA);
  bf16x8 qA1 = *reinterpret_cast<const bf16x8*>(QpA + 32);
  const short* QpB = QpA + 64 * 64;
  bf16x8 qB0 = *reinterpret_cast<const bf16x8*>(QpB);
  bf16x8 qB1 = *reinterpret_cast<const bf16x8*>(QpB + 32);

  floatx4 oA[4], oB[4];
  floatx4 zero = {0.f, 0.f, 0.f, 0.f};
  #pragma unroll
  for (int i = 0; i < 4; ++i) { oA[i] = zero; oB[i] = zero; }
  float mrunA = -1e30f, lrunA = 0.f;     // lrun is a PER-LANE partial (alpha is
  float mrunB = -1e30f, lrunB = 0.f;     // uniform across the 4 lanes of a q-row)

  auto stage = [&](int buf, int t) {
    #pragma unroll
    for (int i = 0; i < 2; ++i) {
      const int cb = (i * 4 + wid) * 64;         // wave-uniform chunk base
      const int c = cb + lane;
      const int r = c >> 3, s = c & 7;
      const int off = (s ^ (r & 7)) << 3;        // pre-swizzled source
      gld16(Kb + (size_t)(t * 64 + r) * 64 + off, &Kl[buf][cb * 8]);
      gld16(Vb + (size_t)r * 1024 + t * 64 + off, &Vl[buf][cb * 8]);
    }
  };

  // softmax for one half: s4 -> pa0/pa1 fragments, updates mrun/lrun/o.
#define SOFTMAX(s4, mrun, lrun, o, pa0, pa1)                                   \
  do {                                                                         \
    float t0 = max3f(s4[0][0], s4[0][1], s4[0][2]);                            \
    float t1 = max3f(s4[0][3], s4[1][0], s4[1][1]);                            \
    float t2 = max3f(s4[1][2], s4[1][3], s4[2][0]);                            \
    float t3 = max3f(s4[2][1], s4[2][2], s4[2][3]);                            \
    float t4 = max3f(s4[3][0], s4[3][1], s4[3][2]);                            \
    float u0 = max3f(t0, t1, t2);                                              \
    float u1 = max3f(t3, t4, s4[3][3]);                                        \
    float m0 = pl_max(fmaxf(u0, u1));                                          \
    if (!__all(m0 - mrun <= 8.f)) {                                            \
      float mnew = fmaxf(mrun, m0);                                            \
      float alpha = pexp(mrun - mnew);                                         \
      mrun = mnew;                                                             \
      lrun *= alpha;                                                           \
      float a4[4];                                                             \
      _Pragma("unroll")                                                        \
      for (int r = 0; r < 4; ++r) a4[r] = __shfl(alpha, slb + r);              \
      _Pragma("unroll")                                                        \
      for (int nt = 0; nt < 4; ++nt) {                                         \
        o[nt][0] *= a4[0]; o[nt][1] *= a4[1];                                  \
        o[nt][2] *= a4[2]; o[nt][3] *= a4[3];                                  \
      }                                                                        \
    }                                                                          \
    unsigned w[4][2];                                                          \
    _Pragma("unroll")                                                          \
    for (int kt = 0; kt < 4; ++kt) {                                           \
      float p0 = pexp(s4[kt][0] - mrun), p1 = pexp(s4[kt][1] - mrun);          \
      float p2 = pexp(s4[kt][2] - mrun), p3 = pexp(s4[kt][3] - mrun);          \
      lrun += (p0 + p1) + (p2 + p3);                                           \
      w[kt][0] = cvtpk(p0, p1);                                                \
      w[kt][1] = cvtpk(p2, p3);                                                \
    }                                                                          \
    unsigned W[2][2][2];                                                       \
    _Pragma("unroll")                                                          \
    for (int ks = 0; ks < 2; ++ks)                                             \
      _Pragma("unroll")                                                        \
      for (int h = 0; h < 2; ++h) {                                            \
        u32x2 y = __builtin_amdgcn_permlane32_swap(w[2 * ks][h],               \
                                                   w[2 * ks + 1][h],           \
                                                   false, false);              \
        u32x2 z = __builtin_amdgcn_permlane16_swap(y[0], y[1], false, false);  \
        W[ks][0][h] = z[0];                                                    \
        W[ks][1][h] = z[1];                                                    \
      }                                                                        \
    u32x4 aw0 = {W[0][0][0], W[0][0][1], W[0][1][0], W[0][1][1]};              \
    u32x4 aw1 = {W[1][0][0], W[1][0][1], W[1][1][0], W[1][1][1]};              \
    pa0 = __builtin_bit_cast(bf16x8, aw0);                                     \
    pa1 = __builtin_bit_cast(bf16x8, aw1);                                     \
  } while (0)

  stage(0, 0);
  __syncthreads();

  for (int t = 0; t < 16; ++t) {
    const int buf = t & 1;
    if (t < 15) stage(buf ^ 1, t + 1);           // loads fly under compute

    // ---- S^T = K Q^T for BOTH halves off shared kf reads: 16 MFMA, 8 ds_read ----
    floatx4 sA[4], sB[4];
    #pragma unroll
    for (int kt = 0; kt < 4; ++kt) { sA[kt] = zero; sB[kt] = zero; }
    __builtin_amdgcn_s_setprio(1);
    #pragma unroll
    for (int kt = 0; kt < 4; ++kt) {
      int krow = kt * 16 + l15;
      int ch0 = (g ^ (krow & 7)) << 3, ch1 = ((4 + g) ^ (krow & 7)) << 3;
      bf16x8 kf0 = *reinterpret_cast<const bf16x8*>(&Kl[buf][krow * 64 + ch0]);
      sA[kt] = __builtin_amdgcn_mfma_f32_16x16x32_bf16(kf0, qA0, sA[kt], 0, 0, 0);
      sB[kt] = __builtin_amdgcn_mfma_f32_16x16x32_bf16(kf0, qB0, sB[kt], 0, 0, 0);
      bf16x8 kf1 = *reinterpret_cast<const bf16x8*>(&Kl[buf][krow * 64 + ch1]);
      sA[kt] = __builtin_amdgcn_mfma_f32_16x16x32_bf16(kf1, qA1, sA[kt], 0, 0, 0);
      sB[kt] = __builtin_amdgcn_mfma_f32_16x16x32_bf16(kf1, qB1, sB[kt], 0, 0, 0);
    }
    __builtin_amdgcn_s_setprio(0);

    // ---- softmax both halves ----
    bf16x8 paA0, paA1, paB0, paB1;
    SOFTMAX(sA, mrunA, lrunA, oA, paA0, paA1);
    SOFTMAX(sB, mrunB, lrunB, oB, paB0, paB1);

    // ---- O += P V for BOTH halves off shared vf reads: 16 MFMA, 8 ds_read ----
    __builtin_amdgcn_s_setprio(1);
    #pragma unroll
    for (int nt = 0; nt < 4; ++nt) {
      int row = nt * 16 + l15;
      int ch0 = (g ^ (row & 7)) << 3, ch1 = ((4 + g) ^ (row & 7)) << 3;
      bf16x8 vf0 = *reinterpret_cast<const bf16x8*>(&Vl[buf][row * 64 + ch0]);
      oA[nt] = __builtin_amdgcn_mfma_f32_16x16x32_bf16(paA0, vf0, oA[nt], 0, 0, 0);
      oB[nt] = __builtin_amdgcn_mfma_f32_16x16x32_bf16(paB0, vf0, oB[nt], 0, 0, 0);
      bf16x8 vf1 = *reinterpret_cast<const bf16x8*>(&Vl[buf][row * 64 + ch1]);
      oA[nt] = __builtin_amdgcn_mfma_f32_16x16x32_bf16(paA1, vf1, oA[nt], 0, 0, 0);
      oB[nt] = __builtin_amdgcn_mfma_f32_16x16x32_bf16(paB1, vf1, oB[nt], 0, 0, 0);
    }
    __builtin_amdgcn_s_setprio(0);
    __syncthreads();   // staged t+1 complete (barrier drains vmcnt); buf reusable
  }

  // ---- epilogue: finish lrun reduction (4 lanes per q-row), write both halves ----
  const int b = bh >> 4, h = bh & 15;
  lrunA += __shfl_xor(lrunA, 16); lrunA += __shfl_xor(lrunA, 32);
  lrunB += __shfl_xor(lrunB, 16); lrunB += __shfl_xor(lrunB, 32);
  float invA = 1.f / lrunA, invB = 1.f / lrunB;
  #pragma unroll
  for (int r = 0; r < 4; ++r) {
    float irA = __shfl(invA, slb + r);
    float irB = __shfl(invB, slb + r);
    int nA = q0 + wid * 16 + g * 4 + r;
    size_t baseA = ((size_t)(b * 1024) + nA) * 1024 + h * 64;
    size_t baseB = baseA + (size_t)64 * 1024;
    #pragma unroll
    for (int nt = 0; nt < 4; ++nt) {
      aout[baseA + nt * 16 + l15] = f2bf(oA[nt][r] * irA);
      aout[baseB + nt * 16 + l15] = f2bf(oB[nt][r] * irB);
    }
  }
#undef SOFTMAX
}

// ---------------------------------------------------------------------------
extern "C" void kernel_launch(void* const* d_in, const int* in_sizes, int n_in,
                              void* d_out, int out_size, void* d_ws, size_t ws_size,
                              hipStream_t stream) {
  const float* x      = (const float*)d_in[0];   // [8,1024,1024]
  const float* ropef  = (const float*)d_in[1];   // [1,1024,1,64]
  const float* qkv_w  = (const float*)d_in[2];   // [3072,1024]
  const float* proj_w = (const float*)d_in[3];   // [1024,1024]
  const float* proj_b = (const float*)d_in[4];   // [1024]
  float* out = (float*)d_out;

  char* ws = (char*)d_ws;
  short*  xb  = (short*)(ws + 0);            // 16 MB  x bf16        (contiguous with)
  short*  wqb = (short*)(ws + 16777216);     //  6 MB  qkv_w bf16    (contiguous with)
  short*  wpb = (short*)(ws + 23068672);     //  2 MB  proj_w bf16
  short*  qb  = (short*)(ws + 25165824);     // 16 MB  q [bh][n][d] (RoPE+scale)
  short*  kb  = (short*)(ws + 41943040);     // 16 MB  k [bh][n][d] (RoPE)
  short*  vtb = (short*)(ws + 58720256);     // 16 MB  v^T [bh][d][n]
  short*  aob = (short*)(ws + 75497472);     // 16 MB  attn out bf16 [B][N][C]
  float2* tbl = (float2*)(ws + 92274688);    // 512 KB cos/sin table

  prep_all<<<12544, 256, 0, stream>>>(x, qkv_w, proj_w, xb, ropef, tbl);

  gemm_qkv_k<<<dim3(24, 64), 256, 0, stream>>>(xb, wqb, tbl, qb, kb, vtb);
  attn_kernel<<<dim3(128, 8), 256, 0, stream>>>(qb, kb, vtb, aob);
  gemm_proj_k<<<dim3(8, 64), 256, 0, stream>>>(aob, wpb, proj_b, out);
}